// Round 2
// baseline (1394.918 us; speedup 1.0000x reference)
//
#include <hip/hip_runtime.h>

#define NN 100000
#define NE 1600000
#define NG 256
#define EPT 2
#define NPT 2

// order-preserving float->uint encoding for atomicMax on floats
__device__ __forceinline__ unsigned fenc(float f) {
    unsigned u = __float_as_uint(f);
    return (u & 0x80000000u) ? ~u : (u | 0x80000000u);
}
__device__ __forceinline__ float fdec(unsigned e) {
    return __uint_as_float((e & 0x80000000u) ? (e & 0x7FFFFFFFu) : ~e);
}

__global__ __launch_bounds__(256) void zero_kernel(float* __restrict__ p, int n) {
    int i = blockIdx.x * 256 + threadIdx.x;
    if (i < n) p[i] = 0.f;
}

// Pre-transpose weights into padded, row-contiguous layouts for scalar loads:
//   ewt: 2 layers x 128 rows x 24 floats  [W1[0..16][j], b1[j], W2[j][0..2], pad x3]
//   nwt: 2 layers x 128 rows x 28 floats  [W1[0..17][j], b1[j], W2[j][0..6], pad x2]
__global__ __launch_bounds__(256) void prep_kernel(
    const float* __restrict__ eW1, const float* __restrict__ eb1, const float* __restrict__ eW2,
    const float* __restrict__ nW1, const float* __restrict__ nb1, const float* __restrict__ nW2,
    float* __restrict__ ewt, float* __restrict__ nwt)
{
    int t = blockIdx.x * 256 + threadIdx.x;
    const int ESZ = 2 * 128 * 24;
    const int NSZ = 2 * 128 * 28;
    if (t < ESZ) {
        int l = t / (128 * 24), rest = t % (128 * 24), j = rest / 24, i = rest % 24;
        float v = 0.f;
        if (i < 17)       v = eW1[l * 17 * 128 + i * 128 + j];
        else if (i == 17) v = eb1[l * 128 + j];
        else if (i < 21)  v = eW2[l * 128 * 3 + j * 3 + (i - 18)];
        ewt[t] = v;
    } else if (t < ESZ + NSZ) {
        int q = t - ESZ;
        int l = q / (128 * 28), rest = q % (128 * 28), j = rest / 28, i = rest % 28;
        float v = 0.f;
        if (i < 18)       v = nW1[l * 18 * 128 + i * 128 + j];
        else if (i == 18) v = nb1[l * 128 + j];
        else if (i < 26)  v = nW2[l * 128 * 7 + j * 7 + (i - 19)];
        nwt[q] = v;
    }
}

// Edge MLP: in = [x[row](7), x[col](7), ea(3)] -> relu(in@W1+b1) @ W2 + b2
// Weights read per-j via uniform scalar loads (SGPRs), inputs live in VGPRs.
// NOTE: grid*256*EPT == NE exactly (3125*512 = 1600000) -> no bounds checks.
__global__ __launch_bounds__(256, 6) void edge_kernel(
    const float* __restrict__ x, const float* __restrict__ ein,
    float* __restrict__ eout,
    const int* __restrict__ row, const int* __restrict__ col,
    const float* __restrict__ wt, const float* __restrict__ b2,
    float* __restrict__ nsum, unsigned* __restrict__ nmax,
    float* __restrict__ ncnt, int count_flag)
{
    int tid = threadIdx.x;
    int e0 = blockIdx.x * (256 * EPT) + tid;

    float in[EPT][17];
    float acc[EPT][3];
    int cols[EPT];

    #pragma unroll
    for (int k = 0; k < EPT; ++k) {
        int e = e0 + k * 256;
        int r = row[e], c = col[e];
        cols[k] = c;
        const float* xr = x + (size_t)r * 7;
        const float* xc = x + (size_t)c * 7;
        #pragma unroll
        for (int i = 0; i < 7; ++i) in[k][i] = xr[i];
        #pragma unroll
        for (int i = 0; i < 7; ++i) in[k][7 + i] = xc[i];
        #pragma unroll
        for (int i = 0; i < 3; ++i) in[k][14 + i] = ein[(size_t)e * 3 + i];
        acc[k][0] = acc[k][1] = acc[k][2] = 0.f;
    }

    for (int j = 0; j < 128; ++j) {
        // force wave-uniform (scalar) weight loads
        const float* wr = wt + __builtin_amdgcn_readfirstlane(j * 24);
        float w[21];
        #pragma unroll
        for (int i = 0; i < 21; ++i) w[i] = wr[i];
        #pragma unroll
        for (int k = 0; k < EPT; ++k) {
            float h = w[17];
            #pragma unroll
            for (int i = 0; i < 17; ++i) h += in[k][i] * w[i];
            h = fmaxf(h, 0.f);
            acc[k][0] += h * w[18];
            acc[k][1] += h * w[19];
            acc[k][2] += h * w[20];
        }
    }

    float bb0 = b2[0], bb1 = b2[1], bb2 = b2[2];
    #pragma unroll
    for (int k = 0; k < EPT; ++k) {
        int e = e0 + k * 256;
        int c = cols[k];
        float o0 = acc[k][0] + bb0, o1 = acc[k][1] + bb1, o2 = acc[k][2] + bb2;
        eout[(size_t)e * 3 + 0] = o0;
        eout[(size_t)e * 3 + 1] = o1;
        eout[(size_t)e * 3 + 2] = o2;
        atomicAdd(&nsum[c * 3 + 0], o0);
        atomicAdd(&nsum[c * 3 + 1], o1);
        atomicAdd(&nsum[c * 3 + 2], o2);
        atomicMax(&nmax[c * 3 + 0], fenc(o0));
        atomicMax(&nmax[c * 3 + 1], fenc(o1));
        atomicMax(&nmax[c * 3 + 2], fenc(o2));
        if (count_flag) atomicAdd(&ncnt[c], 1.0f);
    }
}

// Node MLP: in = [x(7), sum(3), max(3), mean(3), u[batch](2)] (18) -> H=128 -> 7
__global__ __launch_bounds__(256, 6) void node_kernel(
    const float* __restrict__ x_in, const float* __restrict__ nsum,
    const unsigned* __restrict__ nmax, const float* __restrict__ ncnt,
    const float* __restrict__ u, const int* __restrict__ batch,
    const float* __restrict__ wt, const float* __restrict__ b2,
    float* __restrict__ x_out, int do_pool,
    float* __restrict__ gsum, unsigned* __restrict__ gmax, float* __restrict__ gcnt)
{
    int tid = threadIdx.x;
    int n0 = blockIdx.x * (256 * NPT) + tid;

    float in[NPT][18];
    float acc[NPT][7];
    int bt[NPT];

    #pragma unroll
    for (int k = 0; k < NPT; ++k) {
        int n = n0 + k * 256;
        if (n < NN) {
            #pragma unroll
            for (int i = 0; i < 7; ++i) in[k][i] = x_in[(size_t)n * 7 + i];
            float c = ncnt[n];
            #pragma unroll
            for (int i = 0; i < 3; ++i) {
                float s = nsum[n * 3 + i];
                in[k][7 + i] = s;
                in[k][10 + i] = (c > 0.f) ? fdec(nmax[n * 3 + i]) : 0.f;
                in[k][13 + i] = s / fmaxf(c, 1.f);
            }
            int b = batch[n];
            bt[k] = b;
            in[k][16] = u[b * 2 + 0];
            in[k][17] = u[b * 2 + 1];
        } else {
            bt[k] = 0;
            #pragma unroll
            for (int i = 0; i < 18; ++i) in[k][i] = 0.f;
        }
        #pragma unroll
        for (int c = 0; c < 7; ++c) acc[k][c] = 0.f;
    }

    for (int j = 0; j < 128; ++j) {
        const float* wr = wt + __builtin_amdgcn_readfirstlane(j * 28);
        float w[26];
        #pragma unroll
        for (int i = 0; i < 26; ++i) w[i] = wr[i];
        #pragma unroll
        for (int k = 0; k < NPT; ++k) {
            float h = w[18];
            #pragma unroll
            for (int i = 0; i < 18; ++i) h += in[k][i] * w[i];
            h = fmaxf(h, 0.f);
            #pragma unroll
            for (int c = 0; c < 7; ++c) acc[k][c] += h * w[19 + c];
        }
    }

    float bb[7];
    #pragma unroll
    for (int c = 0; c < 7; ++c) bb[c] = b2[c];

    #pragma unroll
    for (int k = 0; k < NPT; ++k) {
        int n = n0 + k * 256;
        if (n < NN) {
            #pragma unroll
            for (int c = 0; c < 7; ++c) {
                float o = acc[k][c] + bb[c];
                x_out[(size_t)n * 7 + c] = o;
                if (do_pool) {
                    atomicAdd(&gsum[bt[k] * 7 + c], o);
                    atomicMax(&gmax[bt[k] * 7 + c], fenc(o));
                }
            }
            if (do_pool) atomicAdd(&gcnt[bt[k]], 1.0f);
        }
    }
}

// Output head: per graph g: in = [sum(7), mean(7), max(7), u(2)] (23)
__global__ __launch_bounds__(128) void head_kernel(
    const float* __restrict__ gsum, const unsigned* __restrict__ gmax,
    const float* __restrict__ gcnt, const float* __restrict__ u,
    const float* __restrict__ oW1, const float* __restrict__ ob1,
    const float* __restrict__ oW2, const float* __restrict__ ob2,
    const float* __restrict__ oW3, const float* __restrict__ ob3,
    const float* __restrict__ oW4, const float* __restrict__ ob4,
    float* __restrict__ out)
{
    int g = blockIdx.x, j = threadIdx.x;
    __shared__ float hin[23];
    __shared__ float ha[128];
    __shared__ float hb[128];
    if (j < 7) {
        float s = gsum[g * 7 + j];
        float c = gcnt[g];
        hin[j] = s;
        hin[7 + j] = s / fmaxf(c, 1.f);
        hin[14 + j] = (c > 0.f) ? fdec(gmax[g * 7 + j]) : 0.f;
    }
    if (j < 2) hin[21 + j] = u[g * 2 + j];
    __syncthreads();

    float h = ob1[j];
    for (int i = 0; i < 23; ++i) h += hin[i] * oW1[i * 128 + j];
    h = fmaxf(h, 0.f);
    ha[j] = h;
    __syncthreads();

    h = ob2[j];
    for (int i = 0; i < 128; ++i) h += ha[i] * oW2[i * 128 + j];
    h = fmaxf(h, 0.f);
    hb[j] = h;
    __syncthreads();

    h = ob3[j];
    for (int i = 0; i < 128; ++i) h += hb[i] * oW3[i * 128 + j];
    h = fmaxf(h, 0.f);
    ha[j] = h * oW4[j];
    __syncthreads();

    if (j == 0) {
        float s = ob4[0];
        for (int i = 0; i < 128; ++i) s += ha[i];
        out[g] = s;
    }
}

extern "C" void kernel_launch(void* const* d_in, const int* in_sizes, int n_in,
                              void* d_out, int out_size, void* d_ws, size_t ws_size,
                              hipStream_t stream) {
    const float* x         = (const float*)d_in[0];
    const float* edge_attr = (const float*)d_in[1];
    const float* u         = (const float*)d_in[2];
    const float* eW1 = (const float*)d_in[3];
    const float* eb1 = (const float*)d_in[4];
    const float* eW2 = (const float*)d_in[5];
    const float* eb2 = (const float*)d_in[6];
    const float* nW1 = (const float*)d_in[7];
    const float* nb1 = (const float*)d_in[8];
    const float* nW2 = (const float*)d_in[9];
    const float* nb2 = (const float*)d_in[10];
    const float* oW1 = (const float*)d_in[11];
    const float* ob1 = (const float*)d_in[12];
    const float* oW2 = (const float*)d_in[13];
    const float* ob2 = (const float*)d_in[14];
    const float* oW3 = (const float*)d_in[15];
    const float* ob3 = (const float*)d_in[16];
    const float* oW4 = (const float*)d_in[17];
    const float* ob4 = (const float*)d_in[18];
    const int* edge_index = (const int*)d_in[19];
    const int* batch      = (const int*)d_in[20];
    const int* row = edge_index;
    const int* col = edge_index + NE;

    float* ws    = (float*)d_ws;
    float* ws_e  = ws;                                  // E*3
    float* ws_x  = ws_e + (size_t)NE * 3;               // N*7
    float* nsum  = ws_x + (size_t)NN * 7;               // N*3
    unsigned* nmax = (unsigned*)(nsum + (size_t)NN * 3);// N*3
    float* ncnt  = (float*)(nmax + (size_t)NN * 3);     // N
    float* gsum  = ncnt + NN;                           // G*7
    unsigned* gmax = (unsigned*)(gsum + NG * 7);        // G*7
    float* gcnt  = (float*)(gmax + NG * 7);             // G
    float* ewt   = gcnt + NG;                           // 2*128*24
    float* nwt   = ewt + 2 * 128 * 24;                  // 2*128*28

    // zero node accumulators (sum+max+cnt = 7N) and graph accums (15G)
    {
        int n = NN * 7;
        zero_kernel<<<(n + 255) / 256, 256, 0, stream>>>(nsum, n);
        int m = NG * 15;
        zero_kernel<<<(m + 255) / 256, 256, 0, stream>>>(gsum, m);
    }
    // transpose/pad weights for scalar-load access
    {
        int t = 2 * 128 * 24 + 2 * 128 * 28;
        prep_kernel<<<(t + 255) / 256, 256, 0, stream>>>(eW1, eb1, eW2, nW1, nb1, nW2, ewt, nwt);
    }

    dim3 eb(256), eg(NE / (256 * EPT));                 // exact: 3125 blocks
    dim3 nb(256), ng((NN + 256 * NPT - 1) / (256 * NPT));

    // ---- layer 0 ----
    edge_kernel<<<eg, eb, 0, stream>>>(x, edge_attr, ws_e, row, col,
        ewt, eb2, nsum, nmax, ncnt, 1);
    node_kernel<<<ng, nb, 0, stream>>>(x, nsum, nmax, ncnt, u, batch,
        nwt, nb2, ws_x, 0, gsum, gmax, gcnt);

    // ---- layer 1 ----
    {
        int n = NN * 6; // re-zero nsum + nmax, keep ncnt (same col distribution)
        zero_kernel<<<(n + 255) / 256, 256, 0, stream>>>(nsum, n);
    }
    edge_kernel<<<eg, eb, 0, stream>>>(ws_x, ws_e, ws_e, row, col,
        ewt + 128 * 24, eb2 + 3, nsum, nmax, ncnt, 0);
    node_kernel<<<ng, nb, 0, stream>>>(ws_x, nsum, nmax, ncnt, u, batch,
        nwt + 128 * 28, nb2 + 7, ws_x, 1, gsum, gmax, gcnt);

    // ---- head ----
    head_kernel<<<NG, 128, 0, stream>>>(gsum, gmax, gcnt, u,
        oW1, ob1, oW2, ob2, oW3, ob3, oW4, ob4, (float*)d_out);
}

// Round 3
// 1393.643 us; speedup vs baseline: 1.0009x; 1.0009x over previous
//
#include <hip/hip_runtime.h>

#define NN 100000
#define NE 1600000
#define NG 256

// order-preserving float->uint encoding for atomicMax on floats
__device__ __forceinline__ unsigned fenc(float f) {
    unsigned u = __float_as_uint(f);
    return (u & 0x80000000u) ? ~u : (u | 0x80000000u);
}
__device__ __forceinline__ float fdec(unsigned e) {
    return __uint_as_float((e & 0x80000000u) ? (e & 0x7FFFFFFFu) : ~e);
}

__global__ __launch_bounds__(256) void zero_kernel(float* __restrict__ p, int n) {
    int i = blockIdx.x * 256 + threadIdx.x;
    if (i < n) p[i] = 0.f;
}

// Pre-transpose weights into padded, row-contiguous layouts for scalar loads:
//   ewt: 2 layers x 128 rows x 24 floats  [W1[0..16][j], b1[j], W2[j][0..2], pad x3]
//   nwt: 2 layers x 128 rows x 28 floats  [W1[0..17][j], b1[j], W2[j][0..6], pad x2]
__global__ __launch_bounds__(256) void prep_kernel(
    const float* __restrict__ eW1, const float* __restrict__ eb1, const float* __restrict__ eW2,
    const float* __restrict__ nW1, const float* __restrict__ nb1, const float* __restrict__ nW2,
    float* __restrict__ ewt, float* __restrict__ nwt)
{
    int t = blockIdx.x * 256 + threadIdx.x;
    const int ESZ = 2 * 128 * 24;
    const int NSZ = 2 * 128 * 28;
    if (t < ESZ) {
        int l = t / (128 * 24), rest = t % (128 * 24), j = rest / 24, i = rest % 24;
        float v = 0.f;
        if (i < 17)       v = eW1[l * 17 * 128 + i * 128 + j];
        else if (i == 17) v = eb1[l * 128 + j];
        else if (i < 21)  v = eW2[l * 128 * 3 + j * 3 + (i - 18)];
        ewt[t] = v;
    } else if (t < ESZ + NSZ) {
        int q = t - ESZ;
        int l = q / (128 * 28), rest = q % (128 * 28), j = rest / 28, i = rest % 28;
        float v = 0.f;
        if (i < 18)       v = nW1[l * 18 * 128 + i * 128 + j];
        else if (i == 18) v = nb1[l * 128 + j];
        else if (i < 26)  v = nW2[l * 128 * 7 + j * 7 + (i - 19)];
        nwt[q] = v;
    }
}

// Edge MLP: in = [x[row](7), x[col](7), ea(3)] -> relu(in@W1+b1) @ W2 + b2
// One edge per thread; inputs held in named VGPRs, pinned with an opaque asm
// so the compiler cannot sink/rematerialize the gather loads into the j-loop.
// grid*256 == NE exactly (6250*256 = 1600000) -> no bounds checks.
__global__ __launch_bounds__(256) void edge_kernel(
    const float* __restrict__ x, const float* __restrict__ ein,
    float* __restrict__ eout,
    const int* __restrict__ row, const int* __restrict__ col,
    const float* __restrict__ wt, const float* __restrict__ b2,
    float* __restrict__ nsum, unsigned* __restrict__ nmax,
    float* __restrict__ ncnt, int count_flag)
{
    int e = blockIdx.x * 256 + threadIdx.x;
    int r = row[e], c = col[e];
    const float* xr = x + (size_t)r * 7;
    const float* xc = x + (size_t)c * 7;
    float i0 = xr[0], i1 = xr[1], i2 = xr[2], i3 = xr[3], i4 = xr[4], i5 = xr[5], i6 = xr[6];
    float i7 = xc[0], i8 = xc[1], i9 = xc[2], i10 = xc[3], i11 = xc[4], i12 = xc[5], i13 = xc[6];
    const float* ep = ein + (size_t)e * 3;
    float i14 = ep[0], i15 = ep[1], i16 = ep[2];

    // pin inputs into VGPRs: loads cannot be sunk past this point
    asm volatile("" : "+v"(i0), "+v"(i1), "+v"(i2), "+v"(i3), "+v"(i4), "+v"(i5),
                      "+v"(i6), "+v"(i7), "+v"(i8), "+v"(i9), "+v"(i10), "+v"(i11),
                      "+v"(i12), "+v"(i13), "+v"(i14), "+v"(i15), "+v"(i16));

    float a0 = 0.f, a1 = 0.f, a2 = 0.f;

    #pragma unroll 2
    for (int j = 0; j < 128; ++j) {
        const float* wr = wt + __builtin_amdgcn_readfirstlane(j * 24);
        float w[21];
        #pragma unroll
        for (int i = 0; i < 21; ++i) w[i] = wr[i];
        // two FMA chains for dependency latency
        float h0 = w[17], h1 = 0.f;
        h0 += i0 * w[0];   h1 += i1 * w[1];
        h0 += i2 * w[2];   h1 += i3 * w[3];
        h0 += i4 * w[4];   h1 += i5 * w[5];
        h0 += i6 * w[6];   h1 += i7 * w[7];
        h0 += i8 * w[8];   h1 += i9 * w[9];
        h0 += i10 * w[10]; h1 += i11 * w[11];
        h0 += i12 * w[12]; h1 += i13 * w[13];
        h0 += i14 * w[14]; h1 += i15 * w[15];
        h0 += i16 * w[16];
        float h = fmaxf(h0 + h1, 0.f);
        a0 += h * w[18];
        a1 += h * w[19];
        a2 += h * w[20];
    }

    float o0 = a0 + b2[0], o1 = a1 + b2[1], o2 = a2 + b2[2];
    eout[(size_t)e * 3 + 0] = o0;
    eout[(size_t)e * 3 + 1] = o1;
    eout[(size_t)e * 3 + 2] = o2;
    atomicAdd(&nsum[c * 3 + 0], o0);
    atomicAdd(&nsum[c * 3 + 1], o1);
    atomicAdd(&nsum[c * 3 + 2], o2);
    atomicMax(&nmax[c * 3 + 0], fenc(o0));
    atomicMax(&nmax[c * 3 + 1], fenc(o1));
    atomicMax(&nmax[c * 3 + 2], fenc(o2));
    if (count_flag) atomicAdd(&ncnt[c], 1.0f);
}

// Node MLP: in = [x(7), sum(3), max(3), mean(3), u[batch](2)] (18) -> H=128 -> 7
__global__ __launch_bounds__(256) void node_kernel(
    const float* __restrict__ x_in, const float* __restrict__ nsum,
    const unsigned* __restrict__ nmax, const float* __restrict__ ncnt,
    const float* __restrict__ u, const int* __restrict__ batch,
    const float* __restrict__ wt, const float* __restrict__ b2,
    float* __restrict__ x_out, int do_pool,
    float* __restrict__ gsum, unsigned* __restrict__ gmax, float* __restrict__ gcnt)
{
    int n = blockIdx.x * 256 + threadIdx.x;
    if (n >= NN) return;

    float i0 = x_in[(size_t)n * 7 + 0], i1 = x_in[(size_t)n * 7 + 1],
          i2 = x_in[(size_t)n * 7 + 2], i3 = x_in[(size_t)n * 7 + 3],
          i4 = x_in[(size_t)n * 7 + 4], i5 = x_in[(size_t)n * 7 + 5],
          i6 = x_in[(size_t)n * 7 + 6];
    float cnt = ncnt[n];
    float s0 = nsum[n * 3 + 0], s1 = nsum[n * 3 + 1], s2 = nsum[n * 3 + 2];
    float inv = 1.f / fmaxf(cnt, 1.f);
    float m0 = (cnt > 0.f) ? fdec(nmax[n * 3 + 0]) : 0.f;
    float m1 = (cnt > 0.f) ? fdec(nmax[n * 3 + 1]) : 0.f;
    float m2 = (cnt > 0.f) ? fdec(nmax[n * 3 + 2]) : 0.f;
    float e0 = s0 * inv, e1 = s1 * inv, e2 = s2 * inv;
    int b = batch[n];
    float u0 = u[b * 2 + 0], u1 = u[b * 2 + 1];

    asm volatile("" : "+v"(i0), "+v"(i1), "+v"(i2), "+v"(i3), "+v"(i4), "+v"(i5),
                      "+v"(i6), "+v"(s0), "+v"(s1), "+v"(s2), "+v"(m0), "+v"(m1),
                      "+v"(m2), "+v"(e0), "+v"(e1), "+v"(e2), "+v"(u0), "+v"(u1));

    float a0 = 0.f, a1 = 0.f, a2 = 0.f, a3 = 0.f, a4 = 0.f, a5 = 0.f, a6 = 0.f;

    #pragma unroll 2
    for (int j = 0; j < 128; ++j) {
        const float* wr = wt + __builtin_amdgcn_readfirstlane(j * 28);
        float w[26];
        #pragma unroll
        for (int i = 0; i < 26; ++i) w[i] = wr[i];
        float h0 = w[18], h1 = 0.f;
        h0 += i0 * w[0];   h1 += i1 * w[1];
        h0 += i2 * w[2];   h1 += i3 * w[3];
        h0 += i4 * w[4];   h1 += i5 * w[5];
        h0 += i6 * w[6];   h1 += s0 * w[7];
        h0 += s1 * w[8];   h1 += s2 * w[9];
        h0 += m0 * w[10];  h1 += m1 * w[11];
        h0 += m2 * w[12];  h1 += e0 * w[13];
        h0 += e1 * w[14];  h1 += e2 * w[15];
        h0 += u0 * w[16];  h1 += u1 * w[17];
        float h = fmaxf(h0 + h1, 0.f);
        a0 += h * w[19]; a1 += h * w[20]; a2 += h * w[21]; a3 += h * w[22];
        a4 += h * w[23]; a5 += h * w[24]; a6 += h * w[25];
    }

    float o[7];
    o[0] = a0 + b2[0]; o[1] = a1 + b2[1]; o[2] = a2 + b2[2]; o[3] = a3 + b2[3];
    o[4] = a4 + b2[4]; o[5] = a5 + b2[5]; o[6] = a6 + b2[6];

    #pragma unroll
    for (int c = 0; c < 7; ++c) x_out[(size_t)n * 7 + c] = o[c];

    if (do_pool) {
        #pragma unroll
        for (int c = 0; c < 7; ++c) {
            atomicAdd(&gsum[b * 7 + c], o[c]);
            atomicMax(&gmax[b * 7 + c], fenc(o[c]));
        }
        atomicAdd(&gcnt[b], 1.0f);
    }
}

// Output head: per graph g: in = [sum(7), mean(7), max(7), u(2)] (23)
__global__ __launch_bounds__(128) void head_kernel(
    const float* __restrict__ gsum, const unsigned* __restrict__ gmax,
    const float* __restrict__ gcnt, const float* __restrict__ u,
    const float* __restrict__ oW1, const float* __restrict__ ob1,
    const float* __restrict__ oW2, const float* __restrict__ ob2,
    const float* __restrict__ oW3, const float* __restrict__ ob3,
    const float* __restrict__ oW4, const float* __restrict__ ob4,
    float* __restrict__ out)
{
    int g = blockIdx.x, j = threadIdx.x;
    __shared__ float hin[23];
    __shared__ float ha[128];
    __shared__ float hb[128];
    if (j < 7) {
        float s = gsum[g * 7 + j];
        float c = gcnt[g];
        hin[j] = s;
        hin[7 + j] = s / fmaxf(c, 1.f);
        hin[14 + j] = (c > 0.f) ? fdec(gmax[g * 7 + j]) : 0.f;
    }
    if (j < 2) hin[21 + j] = u[g * 2 + j];
    __syncthreads();

    float h = ob1[j];
    for (int i = 0; i < 23; ++i) h += hin[i] * oW1[i * 128 + j];
    h = fmaxf(h, 0.f);
    ha[j] = h;
    __syncthreads();

    h = ob2[j];
    for (int i = 0; i < 128; ++i) h += ha[i] * oW2[i * 128 + j];
    h = fmaxf(h, 0.f);
    hb[j] = h;
    __syncthreads();

    h = ob3[j];
    for (int i = 0; i < 128; ++i) h += hb[i] * oW3[i * 128 + j];
    h = fmaxf(h, 0.f);
    ha[j] = h * oW4[j];
    __syncthreads();

    if (j == 0) {
        float s = ob4[0];
        for (int i = 0; i < 128; ++i) s += ha[i];
        out[g] = s;
    }
}

extern "C" void kernel_launch(void* const* d_in, const int* in_sizes, int n_in,
                              void* d_out, int out_size, void* d_ws, size_t ws_size,
                              hipStream_t stream) {
    const float* x         = (const float*)d_in[0];
    const float* edge_attr = (const float*)d_in[1];
    const float* u         = (const float*)d_in[2];
    const float* eW1 = (const float*)d_in[3];
    const float* eb1 = (const float*)d_in[4];
    const float* eW2 = (const float*)d_in[5];
    const float* eb2 = (const float*)d_in[6];
    const float* nW1 = (const float*)d_in[7];
    const float* nb1 = (const float*)d_in[8];
    const float* nW2 = (const float*)d_in[9];
    const float* nb2 = (const float*)d_in[10];
    const float* oW1 = (const float*)d_in[11];
    const float* ob1 = (const float*)d_in[12];
    const float* oW2 = (const float*)d_in[13];
    const float* ob2 = (const float*)d_in[14];
    const float* oW3 = (const float*)d_in[15];
    const float* ob3 = (const float*)d_in[16];
    const float* oW4 = (const float*)d_in[17];
    const float* ob4 = (const float*)d_in[18];
    const int* edge_index = (const int*)d_in[19];
    const int* batch      = (const int*)d_in[20];
    const int* row = edge_index;
    const int* col = edge_index + NE;

    float* ws    = (float*)d_ws;
    float* ws_e  = ws;                                  // E*3
    float* ws_x  = ws_e + (size_t)NE * 3;               // N*7
    float* nsum  = ws_x + (size_t)NN * 7;               // N*3
    unsigned* nmax = (unsigned*)(nsum + (size_t)NN * 3);// N*3
    float* ncnt  = (float*)(nmax + (size_t)NN * 3);     // N
    float* gsum  = ncnt + NN;                           // G*7
    unsigned* gmax = (unsigned*)(gsum + NG * 7);        // G*7
    float* gcnt  = (float*)(gmax + NG * 7);             // G
    float* ewt   = gcnt + NG;                           // 2*128*24
    float* nwt   = ewt + 2 * 128 * 24;                  // 2*128*28

    // zero node accumulators (sum+max+cnt = 7N) and graph accums (15G)
    {
        int n = NN * 7;
        zero_kernel<<<(n + 255) / 256, 256, 0, stream>>>(nsum, n);
        int m = NG * 15;
        zero_kernel<<<(m + 255) / 256, 256, 0, stream>>>(gsum, m);
    }
    // transpose/pad weights for scalar-load access
    {
        int t = 2 * 128 * 24 + 2 * 128 * 28;
        prep_kernel<<<(t + 255) / 256, 256, 0, stream>>>(eW1, eb1, eW2, nW1, nb1, nW2, ewt, nwt);
    }

    dim3 eb(256), eg(NE / 256);                         // exact: 6250 blocks
    dim3 nb(256), ng((NN + 255) / 256);

    // ---- layer 0 ----
    edge_kernel<<<eg, eb, 0, stream>>>(x, edge_attr, ws_e, row, col,
        ewt, eb2, nsum, nmax, ncnt, 1);
    node_kernel<<<ng, nb, 0, stream>>>(x, nsum, nmax, ncnt, u, batch,
        nwt, nb2, ws_x, 0, gsum, gmax, gcnt);

    // ---- layer 1 ----
    {
        int n = NN * 6; // re-zero nsum + nmax, keep ncnt (same col distribution)
        zero_kernel<<<(n + 255) / 256, 256, 0, stream>>>(nsum, n);
    }
    edge_kernel<<<eg, eb, 0, stream>>>(ws_x, ws_e, ws_e, row, col,
        ewt + 128 * 24, eb2 + 3, nsum, nmax, ncnt, 0);
    node_kernel<<<ng, nb, 0, stream>>>(ws_x, nsum, nmax, ncnt, u, batch,
        nwt + 128 * 28, nb2 + 7, ws_x, 1, gsum, gmax, gcnt);

    // ---- head ----
    head_kernel<<<NG, 128, 0, stream>>>(gsum, gmax, gcnt, u,
        oW1, ob1, oW2, ob2, oW3, ob3, oW4, ob4, (float*)d_out);
}

// Round 4
// 872.527 us; speedup vs baseline: 1.5987x; 1.5972x over previous
//
#include <hip/hip_runtime.h>

#define NN 100000
#define NE 1600000
#define NG 256
#define NB 391   // ceil(NN/256)

// order-preserving float->uint encoding for atomicMax on floats (graph pool)
__device__ __forceinline__ unsigned fenc(float f) {
    unsigned u = __float_as_uint(f);
    return (u & 0x80000000u) ? ~u : (u | 0x80000000u);
}
__device__ __forceinline__ float fdec(unsigned e) {
    return __uint_as_float((e & 0x80000000u) ? (e & 0x7FFFFFFFu) : ~e);
}

__global__ __launch_bounds__(256) void zero_kernel(float* __restrict__ p, int n) {
    int i = blockIdx.x * 256 + threadIdx.x;
    if (i < n) p[i] = 0.f;
}

// ---------------- CSR build ----------------
__global__ __launch_bounds__(256) void count_kernel(
    const int* __restrict__ col, unsigned* __restrict__ cnt) {
    int e = blockIdx.x * 256 + threadIdx.x;       // grid covers NE exactly
    atomicAdd(&cnt[col[e]], 1u);
}

__global__ __launch_bounds__(256) void bsum_kernel(
    const unsigned* __restrict__ cnt, unsigned* __restrict__ bsum) {
    __shared__ unsigned sm[256];
    int i = blockIdx.x * 256 + threadIdx.x;
    sm[threadIdx.x] = (i < NN) ? cnt[i] : 0u;
    __syncthreads();
    for (int s = 128; s > 0; s >>= 1) {
        if (threadIdx.x < s) sm[threadIdx.x] += sm[threadIdx.x + s];
        __syncthreads();
    }
    if (threadIdx.x == 0) bsum[blockIdx.x] = sm[0];
}

__global__ __launch_bounds__(512) void bscan_kernel(
    const unsigned* __restrict__ bsum, unsigned* __restrict__ boff) {
    __shared__ unsigned a[512], b[512];
    int t = threadIdx.x;
    a[t] = (t < NB) ? bsum[t] : 0u;
    __syncthreads();
    unsigned* src = a; unsigned* dst = b;
    for (int off = 1; off < 512; off <<= 1) {
        unsigned v = src[t];
        if (t >= off) v += src[t - off];
        dst[t] = v;
        __syncthreads();
        unsigned* tmp = src; src = dst; dst = tmp;
    }
    if (t < NB) boff[t] = (t == 0) ? 0u : src[t - 1];
}

__global__ __launch_bounds__(256) void start_kernel(
    const unsigned* __restrict__ cnt, const unsigned* __restrict__ boff,
    unsigned* __restrict__ start, unsigned* __restrict__ cursor) {
    __shared__ unsigned a[256], b[256];
    int t = threadIdx.x;
    int i = blockIdx.x * 256 + t;
    unsigned v = (i < NN) ? cnt[i] : 0u;
    a[t] = v;
    __syncthreads();
    unsigned* src = a; unsigned* dst = b;
    for (int off = 1; off < 256; off <<= 1) {
        unsigned x = src[t];
        if (t >= off) x += src[t - off];
        dst[t] = x;
        __syncthreads();
        unsigned* tmp = src; src = dst; dst = tmp;
    }
    unsigned excl = src[t] - v;
    unsigned st = boff[blockIdx.x] + excl;
    if (i < NN) {
        start[i] = st;
        cursor[i] = st;
        if (i == NN - 1) start[NN] = st + v;
    }
}

__global__ __launch_bounds__(256) void scatter_kernel(
    const int* __restrict__ row, const int* __restrict__ col,
    const float* __restrict__ ea,
    unsigned* __restrict__ cursor, int2* __restrict__ rc, float* __restrict__ eab) {
    int e = blockIdx.x * 256 + threadIdx.x;       // grid covers NE exactly
    int c = col[e];
    unsigned t = atomicAdd(&cursor[c], 1u);
    rc[t] = make_int2(row[e], c);
    eab[(size_t)t * 3 + 0] = ea[(size_t)e * 3 + 0];
    eab[(size_t)t * 3 + 1] = ea[(size_t)e * 3 + 1];
    eab[(size_t)t * 3 + 2] = ea[(size_t)e * 3 + 2];
}

// ---------------- weight prep (padded rows for scalar loads) ----------------
//   ewt: 2 x 128 x 24  [W1[0..16][j], b1[j], W2[j][0..2], pad x3]
//   nwt: 2 x 128 x 28  [W1[0..17][j], b1[j], W2[j][0..6], pad x2]
__global__ __launch_bounds__(256) void prep_kernel(
    const float* __restrict__ eW1, const float* __restrict__ eb1, const float* __restrict__ eW2,
    const float* __restrict__ nW1, const float* __restrict__ nb1, const float* __restrict__ nW2,
    float* __restrict__ ewt, float* __restrict__ nwt)
{
    int t = blockIdx.x * 256 + threadIdx.x;
    const int ESZ = 2 * 128 * 24;
    const int NSZ = 2 * 128 * 28;
    if (t < ESZ) {
        int l = t / (128 * 24), rest = t % (128 * 24), j = rest / 24, i = rest % 24;
        float v = 0.f;
        if (i < 17)       v = eW1[l * 17 * 128 + i * 128 + j];
        else if (i == 17) v = eb1[l * 128 + j];
        else if (i < 21)  v = eW2[l * 128 * 3 + j * 3 + (i - 18)];
        ewt[t] = v;
    } else if (t < ESZ + NSZ) {
        int q = t - ESZ;
        int l = q / (128 * 28), rest = q % (128 * 28), j = rest / 28, i = rest % 28;
        float v = 0.f;
        if (i < 18)       v = nW1[l * 18 * 128 + i * 128 + j];
        else if (i == 18) v = nb1[l * 128 + j];
        else if (i < 26)  v = nW2[l * 128 * 7 + j * 7 + (i - 19)];
        nwt[q] = v;
    }
}

// ---------------- edge MLP (sorted order, zero atomics, in-place ea) --------
__global__ __launch_bounds__(256) void edge_kernel(
    const float* __restrict__ x, float* eab,
    const int2* __restrict__ rc,
    const float* __restrict__ wt, const float* __restrict__ b2)
{
    int t = blockIdx.x * 256 + threadIdx.x;       // grid covers NE exactly
    int2 p = rc[t];
    const float* xr = x + (size_t)p.x * 7;
    const float* xc = x + (size_t)p.y * 7;
    float i0 = xr[0], i1 = xr[1], i2 = xr[2], i3 = xr[3], i4 = xr[4], i5 = xr[5], i6 = xr[6];
    float i7 = xc[0], i8 = xc[1], i9 = xc[2], i10 = xc[3], i11 = xc[4], i12 = xc[5], i13 = xc[6];
    float i14 = eab[(size_t)t * 3 + 0], i15 = eab[(size_t)t * 3 + 1], i16 = eab[(size_t)t * 3 + 2];

    asm volatile("" : "+v"(i0), "+v"(i1), "+v"(i2), "+v"(i3), "+v"(i4), "+v"(i5),
                      "+v"(i6), "+v"(i7), "+v"(i8), "+v"(i9), "+v"(i10), "+v"(i11),
                      "+v"(i12), "+v"(i13), "+v"(i14), "+v"(i15), "+v"(i16));

    float a0 = 0.f, a1 = 0.f, a2 = 0.f;

    #pragma unroll 2
    for (int j = 0; j < 128; ++j) {
        const float* wr = wt + __builtin_amdgcn_readfirstlane(j * 24);
        float w[21];
        #pragma unroll
        for (int i = 0; i < 21; ++i) w[i] = wr[i];
        float h0 = w[17], h1 = 0.f;
        h0 += i0 * w[0];   h1 += i1 * w[1];
        h0 += i2 * w[2];   h1 += i3 * w[3];
        h0 += i4 * w[4];   h1 += i5 * w[5];
        h0 += i6 * w[6];   h1 += i7 * w[7];
        h0 += i8 * w[8];   h1 += i9 * w[9];
        h0 += i10 * w[10]; h1 += i11 * w[11];
        h0 += i12 * w[12]; h1 += i13 * w[13];
        h0 += i14 * w[14]; h1 += i15 * w[15];
        h0 += i16 * w[16];
        float h = fmaxf(h0 + h1, 0.f);
        a0 += h * w[18];
        a1 += h * w[19];
        a2 += h * w[20];
    }

    eab[(size_t)t * 3 + 0] = a0 + b2[0];
    eab[(size_t)t * 3 + 1] = a1 + b2[1];
    eab[(size_t)t * 3 + 2] = a2 + b2[2];
}

// ---------------- node: CSR segment reduce + MLP ----------------
__global__ __launch_bounds__(256) void node_kernel(
    const float* x_in, const float* __restrict__ eab,
    const unsigned* __restrict__ start,
    const float* __restrict__ u, const int* __restrict__ batch,
    const float* __restrict__ wt, const float* __restrict__ b2,
    float* x_out, int do_pool,
    float* __restrict__ gsum, unsigned* __restrict__ gmax, float* __restrict__ gcnt)
{
    int n = blockIdx.x * 256 + threadIdx.x;
    if (n >= NN) return;

    unsigned sbeg = start[n], send = start[n + 1];
    float deg = (float)(send - sbeg);

    float s0 = 0.f, s1 = 0.f, s2 = 0.f;
    float m0 = -__builtin_inff(), m1 = -__builtin_inff(), m2 = -__builtin_inff();
    for (unsigned k = sbeg; k < send; ++k) {
        float v0 = eab[(size_t)k * 3 + 0];
        float v1 = eab[(size_t)k * 3 + 1];
        float v2 = eab[(size_t)k * 3 + 2];
        s0 += v0; s1 += v1; s2 += v2;
        m0 = fmaxf(m0, v0); m1 = fmaxf(m1, v1); m2 = fmaxf(m2, v2);
    }
    if (send == sbeg) { m0 = m1 = m2 = 0.f; }
    float inv = 1.f / fmaxf(deg, 1.f);
    float e0 = s0 * inv, e1 = s1 * inv, e2 = s2 * inv;

    float i0 = x_in[(size_t)n * 7 + 0], i1 = x_in[(size_t)n * 7 + 1],
          i2 = x_in[(size_t)n * 7 + 2], i3 = x_in[(size_t)n * 7 + 3],
          i4 = x_in[(size_t)n * 7 + 4], i5 = x_in[(size_t)n * 7 + 5],
          i6 = x_in[(size_t)n * 7 + 6];
    int b = batch[n];
    float u0 = u[b * 2 + 0], u1 = u[b * 2 + 1];

    asm volatile("" : "+v"(i0), "+v"(i1), "+v"(i2), "+v"(i3), "+v"(i4), "+v"(i5),
                      "+v"(i6), "+v"(s0), "+v"(s1), "+v"(s2), "+v"(m0), "+v"(m1),
                      "+v"(m2), "+v"(e0), "+v"(e1), "+v"(e2), "+v"(u0), "+v"(u1));

    float a0 = 0.f, a1 = 0.f, a2 = 0.f, a3 = 0.f, a4 = 0.f, a5 = 0.f, a6 = 0.f;

    #pragma unroll 2
    for (int j = 0; j < 128; ++j) {
        const float* wr = wt + __builtin_amdgcn_readfirstlane(j * 28);
        float w[26];
        #pragma unroll
        for (int i = 0; i < 26; ++i) w[i] = wr[i];
        float h0 = w[18], h1 = 0.f;
        h0 += i0 * w[0];   h1 += i1 * w[1];
        h0 += i2 * w[2];   h1 += i3 * w[3];
        h0 += i4 * w[4];   h1 += i5 * w[5];
        h0 += i6 * w[6];   h1 += s0 * w[7];
        h0 += s1 * w[8];   h1 += s2 * w[9];
        h0 += m0 * w[10];  h1 += m1 * w[11];
        h0 += m2 * w[12];  h1 += e0 * w[13];
        h0 += e1 * w[14];  h1 += e2 * w[15];
        h0 += u0 * w[16];  h1 += u1 * w[17];
        float h = fmaxf(h0 + h1, 0.f);
        a0 += h * w[19]; a1 += h * w[20]; a2 += h * w[21]; a3 += h * w[22];
        a4 += h * w[23]; a5 += h * w[24]; a6 += h * w[25];
    }

    float o[7];
    o[0] = a0 + b2[0]; o[1] = a1 + b2[1]; o[2] = a2 + b2[2]; o[3] = a3 + b2[3];
    o[4] = a4 + b2[4]; o[5] = a5 + b2[5]; o[6] = a6 + b2[6];

    #pragma unroll
    for (int c = 0; c < 7; ++c) x_out[(size_t)n * 7 + c] = o[c];

    if (do_pool) {
        #pragma unroll
        for (int c = 0; c < 7; ++c) {
            atomicAdd(&gsum[b * 7 + c], o[c]);
            atomicMax(&gmax[b * 7 + c], fenc(o[c]));
        }
        atomicAdd(&gcnt[b], 1.0f);
    }
}

// ---------------- output head ----------------
__global__ __launch_bounds__(128) void head_kernel(
    const float* __restrict__ gsum, const unsigned* __restrict__ gmax,
    const float* __restrict__ gcnt, const float* __restrict__ u,
    const float* __restrict__ oW1, const float* __restrict__ ob1,
    const float* __restrict__ oW2, const float* __restrict__ ob2,
    const float* __restrict__ oW3, const float* __restrict__ ob3,
    const float* __restrict__ oW4, const float* __restrict__ ob4,
    float* __restrict__ out)
{
    int g = blockIdx.x, j = threadIdx.x;
    __shared__ float hin[23];
    __shared__ float ha[128];
    __shared__ float hb[128];
    if (j < 7) {
        float s = gsum[g * 7 + j];
        float c = gcnt[g];
        hin[j] = s;
        hin[7 + j] = s / fmaxf(c, 1.f);
        hin[14 + j] = (c > 0.f) ? fdec(gmax[g * 7 + j]) : 0.f;
    }
    if (j < 2) hin[21 + j] = u[g * 2 + j];
    __syncthreads();

    float h = ob1[j];
    for (int i = 0; i < 23; ++i) h += hin[i] * oW1[i * 128 + j];
    h = fmaxf(h, 0.f);
    ha[j] = h;
    __syncthreads();

    h = ob2[j];
    for (int i = 0; i < 128; ++i) h += ha[i] * oW2[i * 128 + j];
    h = fmaxf(h, 0.f);
    hb[j] = h;
    __syncthreads();

    h = ob3[j];
    for (int i = 0; i < 128; ++i) h += hb[i] * oW3[i * 128 + j];
    h = fmaxf(h, 0.f);
    ha[j] = h * oW4[j];
    __syncthreads();

    if (j == 0) {
        float s = ob4[0];
        for (int i = 0; i < 128; ++i) s += ha[i];
        out[g] = s;
    }
}

extern "C" void kernel_launch(void* const* d_in, const int* in_sizes, int n_in,
                              void* d_out, int out_size, void* d_ws, size_t ws_size,
                              hipStream_t stream) {
    const float* x         = (const float*)d_in[0];
    const float* edge_attr = (const float*)d_in[1];
    const float* u         = (const float*)d_in[2];
    const float* eW1 = (const float*)d_in[3];
    const float* eb1 = (const float*)d_in[4];
    const float* eW2 = (const float*)d_in[5];
    const float* eb2 = (const float*)d_in[6];
    const float* nW1 = (const float*)d_in[7];
    const float* nb1 = (const float*)d_in[8];
    const float* nW2 = (const float*)d_in[9];
    const float* nb2 = (const float*)d_in[10];
    const float* oW1 = (const float*)d_in[11];
    const float* ob1 = (const float*)d_in[12];
    const float* oW2 = (const float*)d_in[13];
    const float* ob2 = (const float*)d_in[14];
    const float* oW3 = (const float*)d_in[15];
    const float* ob3 = (const float*)d_in[16];
    const float* oW4 = (const float*)d_in[17];
    const float* ob4 = (const float*)d_in[18];
    const int* edge_index = (const int*)d_in[19];
    const int* batch      = (const int*)d_in[20];
    const int* row = edge_index;
    const int* col = edge_index + NE;

    // workspace layout (floats unless noted)
    float* ws      = (float*)d_ws;
    float* eab     = ws;                                   // E*3        (19.2 MB)
    float* ws_x    = eab + (size_t)NE * 3;                 // N*7        (2.8 MB)
    int2*  rc      = (int2*)(ws_x + (size_t)NN * 7);       // E int2     (12.8 MB)
    unsigned* cnt  = (unsigned*)(rc + (size_t)NE);         // N
    unsigned* startv = cnt + NN;                           // N+1
    unsigned* cursor = startv + NN + 1;                    // N
    unsigned* bsum = cursor + NN;                          // 512
    unsigned* boff = bsum + 512;                           // 512
    float* gsum    = (float*)(boff + 512);                 // 7G
    unsigned* gmax = (unsigned*)(gsum + NG * 7);           // 7G
    float* gcnt    = (float*)(gmax + NG * 7);              // G
    float* ewt     = gcnt + NG;                            // 2*128*24
    float* nwt     = ewt + 2 * 128 * 24;                   // 2*128*28

    dim3 b256(256);
    dim3 ge(NE / 256);        // 6250, exact
    dim3 gn(NB);              // 391

    // ---- zero build/pool accumulators ----
    zero_kernel<<<(NN + 255) / 256, b256, 0, stream>>>((float*)cnt, NN);
    zero_kernel<<<1, b256, 0, stream>>>(gsum, NG * 15 / 256 * 256 == NG * 15 ? NG * 15 : NG * 15); // 3840
    // (NG*15 = 3840 > 256; launch proper grid)
    zero_kernel<<<(NG * 15 + 255) / 256, b256, 0, stream>>>(gsum, NG * 15);

    // ---- CSR build ----
    count_kernel<<<ge, b256, 0, stream>>>(col, cnt);
    bsum_kernel<<<gn, b256, 0, stream>>>(cnt, bsum);
    bscan_kernel<<<1, 512, 0, stream>>>(bsum, boff);
    start_kernel<<<gn, b256, 0, stream>>>(cnt, boff, startv, cursor);
    scatter_kernel<<<ge, b256, 0, stream>>>(row, col, edge_attr, cursor, rc, eab);

    // ---- weight prep ----
    {
        int t = 2 * 128 * 24 + 2 * 128 * 28;
        prep_kernel<<<(t + 255) / 256, b256, 0, stream>>>(eW1, eb1, eW2, nW1, nb1, nW2, ewt, nwt);
    }

    // ---- layer 0 ----
    edge_kernel<<<ge, b256, 0, stream>>>(x, eab, rc, ewt, eb2);
    node_kernel<<<gn, b256, 0, stream>>>(x, eab, startv, u, batch,
        nwt, nb2, ws_x, 0, gsum, gmax, gcnt);

    // ---- layer 1 ----
    edge_kernel<<<ge, b256, 0, stream>>>(ws_x, eab, rc, ewt + 128 * 24, eb2 + 3);
    node_kernel<<<gn, b256, 0, stream>>>(ws_x, eab, startv, u, batch,
        nwt + 128 * 28, nb2 + 7, ws_x, 1, gsum, gmax, gcnt);

    // ---- head ----
    head_kernel<<<NG, 128, 0, stream>>>(gsum, gmax, gcnt, u,
        oW1, ob1, oW2, ob2, oW3, ob3, oW4, ob4, (float*)d_out);
}

// Round 5
// 797.790 us; speedup vs baseline: 1.7485x; 1.0937x over previous
//
#include <hip/hip_runtime.h>

#define NN 100000
#define NE 1600000
#define NG 256
#define NB 391   // ceil(NN/256)

__device__ __forceinline__ float fmax7(float a, float b) { return fmaxf(a, b); }

__global__ __launch_bounds__(256) void zero_kernel(float* __restrict__ p, int n) {
    int i = blockIdx.x * 256 + threadIdx.x;
    if (i < n) p[i] = 0.f;
}

// ---------------- CSR build ----------------
__global__ __launch_bounds__(256) void count_kernel(
    const int* __restrict__ col, unsigned* __restrict__ cnt) {
    int e = blockIdx.x * 256 + threadIdx.x;       // grid covers NE exactly
    atomicAdd(&cnt[col[e]], 1u);
}

__global__ __launch_bounds__(256) void gdeg_kernel(
    const int* __restrict__ batch, unsigned* __restrict__ gdeg) {
    int n = blockIdx.x * 256 + threadIdx.x;
    if (n < NN) atomicAdd(&gdeg[batch[n]], 1u);
}

__global__ __launch_bounds__(256) void bsum_kernel(
    const unsigned* __restrict__ cnt, unsigned* __restrict__ bsum) {
    __shared__ unsigned sm[256];
    int i = blockIdx.x * 256 + threadIdx.x;
    sm[threadIdx.x] = (i < NN) ? cnt[i] : 0u;
    __syncthreads();
    for (int s = 128; s > 0; s >>= 1) {
        if (threadIdx.x < s) sm[threadIdx.x] += sm[threadIdx.x + s];
        __syncthreads();
    }
    if (threadIdx.x == 0) bsum[blockIdx.x] = sm[0];
}

__global__ __launch_bounds__(512) void bscan_kernel(
    const unsigned* __restrict__ bsum, unsigned* __restrict__ boff) {
    __shared__ unsigned a[512], b[512];
    int t = threadIdx.x;
    a[t] = (t < NB) ? bsum[t] : 0u;
    __syncthreads();
    unsigned* src = a; unsigned* dst = b;
    for (int off = 1; off < 512; off <<= 1) {
        unsigned v = src[t];
        if (t >= off) v += src[t - off];
        dst[t] = v;
        __syncthreads();
        unsigned* tmp = src; src = dst; dst = tmp;
    }
    if (t < NB) boff[t] = (t == 0) ? 0u : src[t - 1];
}

__global__ __launch_bounds__(256) void start_kernel(
    const unsigned* __restrict__ cnt, const unsigned* __restrict__ boff,
    unsigned* __restrict__ start, unsigned* __restrict__ cursor) {
    __shared__ unsigned a[256], b[256];
    int t = threadIdx.x;
    int i = blockIdx.x * 256 + t;
    unsigned v = (i < NN) ? cnt[i] : 0u;
    a[t] = v;
    __syncthreads();
    unsigned* src = a; unsigned* dst = b;
    for (int off = 1; off < 256; off <<= 1) {
        unsigned x = src[t];
        if (t >= off) x += src[t - off];
        dst[t] = x;
        __syncthreads();
        unsigned* tmp = src; src = dst; dst = tmp;
    }
    unsigned excl = src[t] - v;
    unsigned st = boff[blockIdx.x] + excl;
    if (i < NN) {
        start[i] = st;
        cursor[i] = st;
        if (i == NN - 1) start[NN] = st + v;
    }
}

__global__ __launch_bounds__(256) void gscan_kernel(
    const unsigned* __restrict__ gdeg, int* __restrict__ gstart) {
    __shared__ unsigned a[256], b[256];
    int t = threadIdx.x;
    a[t] = gdeg[t];
    __syncthreads();
    unsigned* src = a; unsigned* dst = b;
    for (int off = 1; off < 256; off <<= 1) {   // 8 iters -> src == a at end
        unsigned v = src[t];
        if (t >= off) v += src[t - off];
        dst[t] = v;
        __syncthreads();
        unsigned* tmp = src; src = dst; dst = tmp;
    }
    if (t == 0) gstart[0] = 0;
    gstart[t + 1] = (int)src[t];
}

__global__ __launch_bounds__(256) void scatter_kernel(
    const int* __restrict__ row, const int* __restrict__ col,
    const float* __restrict__ ea,
    unsigned* __restrict__ cursor, int2* __restrict__ rc, float* __restrict__ eab) {
    int e = blockIdx.x * 256 + threadIdx.x;       // grid covers NE exactly
    int c = col[e];
    unsigned t = atomicAdd(&cursor[c], 1u);
    rc[t] = make_int2(row[e], c);
    eab[(size_t)t * 3 + 0] = ea[(size_t)e * 3 + 0];
    eab[(size_t)t * 3 + 1] = ea[(size_t)e * 3 + 1];
    eab[(size_t)t * 3 + 2] = ea[(size_t)e * 3 + 2];
}

// ---------------- weight prep (padded rows) ----------------
//   ewt: 2 x 128 x 24  [W1[0..16][j], b1[j], W2[j][0..2], pad x3]
//   nwt: 2 x 128 x 28  [W1[0..17][j], b1[j], W2[j][0..6], pad x2]
__global__ __launch_bounds__(256) void prep_kernel(
    const float* __restrict__ eW1, const float* __restrict__ eb1, const float* __restrict__ eW2,
    const float* __restrict__ nW1, const float* __restrict__ nb1, const float* __restrict__ nW2,
    float* __restrict__ ewt, float* __restrict__ nwt)
{
    int t = blockIdx.x * 256 + threadIdx.x;
    const int ESZ = 2 * 128 * 24;
    const int NSZ = 2 * 128 * 28;
    if (t < ESZ) {
        int l = t / (128 * 24), rest = t % (128 * 24), j = rest / 24, i = rest % 24;
        float v = 0.f;
        if (i < 17)       v = eW1[l * 17 * 128 + i * 128 + j];
        else if (i == 17) v = eb1[l * 128 + j];
        else if (i < 21)  v = eW2[l * 128 * 3 + j * 3 + (i - 18)];
        ewt[t] = v;
    } else if (t < ESZ + NSZ) {
        int q = t - ESZ;
        int l = q / (128 * 28), rest = q % (128 * 28), j = rest / 28, i = rest % 28;
        float v = 0.f;
        if (i < 18)       v = nW1[l * 18 * 128 + i * 128 + j];
        else if (i == 18) v = nb1[l * 128 + j];
        else if (i < 26)  v = nW2[l * 128 * 7 + j * 7 + (i - 19)];
        nwt[q] = v;
    }
}

// ---------------- edge MLP (sorted order, zero atomics, in-place ea) --------
__global__ __launch_bounds__(256) void edge_kernel(
    const float* __restrict__ x, float* eab,
    const int2* __restrict__ rc,
    const float* __restrict__ wt, const float* __restrict__ b2)
{
    int t = blockIdx.x * 256 + threadIdx.x;       // grid covers NE exactly
    int2 p = rc[t];
    const float* xr = x + (size_t)p.x * 7;
    const float* xc = x + (size_t)p.y * 7;
    float i0 = xr[0], i1 = xr[1], i2 = xr[2], i3 = xr[3], i4 = xr[4], i5 = xr[5], i6 = xr[6];
    float i7 = xc[0], i8 = xc[1], i9 = xc[2], i10 = xc[3], i11 = xc[4], i12 = xc[5], i13 = xc[6];
    float i14 = eab[(size_t)t * 3 + 0], i15 = eab[(size_t)t * 3 + 1], i16 = eab[(size_t)t * 3 + 2];

    asm volatile("" : "+v"(i0), "+v"(i1), "+v"(i2), "+v"(i3), "+v"(i4), "+v"(i5),
                      "+v"(i6), "+v"(i7), "+v"(i8), "+v"(i9), "+v"(i10), "+v"(i11),
                      "+v"(i12), "+v"(i13), "+v"(i14), "+v"(i15), "+v"(i16));

    float a0 = 0.f, a1 = 0.f, a2 = 0.f;

    #pragma unroll 2
    for (int j = 0; j < 128; ++j) {
        const float* wr = wt + __builtin_amdgcn_readfirstlane(j * 24);
        float w[21];
        #pragma unroll
        for (int i = 0; i < 21; ++i) w[i] = wr[i];
        float h0 = w[17], h1 = 0.f;
        h0 += i0 * w[0];   h1 += i1 * w[1];
        h0 += i2 * w[2];   h1 += i3 * w[3];
        h0 += i4 * w[4];   h1 += i5 * w[5];
        h0 += i6 * w[6];   h1 += i7 * w[7];
        h0 += i8 * w[8];   h1 += i9 * w[9];
        h0 += i10 * w[10]; h1 += i11 * w[11];
        h0 += i12 * w[12]; h1 += i13 * w[13];
        h0 += i14 * w[14]; h1 += i15 * w[15];
        h0 += i16 * w[16];
        float h = fmaxf(h0 + h1, 0.f);
        a0 += h * w[18];
        a1 += h * w[19];
        a2 += h * w[20];
    }

    eab[(size_t)t * 3 + 0] = a0 + b2[0];
    eab[(size_t)t * 3 + 1] = a1 + b2[1];
    eab[(size_t)t * 3 + 2] = a2 + b2[2];
}

// ---------------- segment reduce: 16 lanes per node ----------------
// writes nred[n][12] = [s0,s1,s2, m0,m1,m2, mean0,mean1,mean2, u0,u1, pad]
__global__ __launch_bounds__(256) void reduce_kernel(
    const float* __restrict__ eab, const unsigned* __restrict__ start,
    const float* __restrict__ u, const int* __restrict__ batch,
    float* __restrict__ nred)
{
    int gid = blockIdx.x * 256 + threadIdx.x;
    int n = gid >> 4, sub = gid & 15;
    if (n >= NN) return;
    unsigned sbeg = start[n], send = start[n + 1];

    float s0 = 0.f, s1 = 0.f, s2 = 0.f;
    float m0 = -__builtin_inff(), m1 = -__builtin_inff(), m2 = -__builtin_inff();
    for (unsigned k = sbeg + sub; k < send; k += 16) {
        float v0 = eab[(size_t)k * 3 + 0];
        float v1 = eab[(size_t)k * 3 + 1];
        float v2 = eab[(size_t)k * 3 + 2];
        s0 += v0; s1 += v1; s2 += v2;
        m0 = fmaxf(m0, v0); m1 = fmaxf(m1, v1); m2 = fmaxf(m2, v2);
    }
    #pragma unroll
    for (int msk = 1; msk < 16; msk <<= 1) {
        s0 += __shfl_xor(s0, msk, 16);
        s1 += __shfl_xor(s1, msk, 16);
        s2 += __shfl_xor(s2, msk, 16);
        m0 = fmaxf(m0, __shfl_xor(m0, msk, 16));
        m1 = fmaxf(m1, __shfl_xor(m1, msk, 16));
        m2 = fmaxf(m2, __shfl_xor(m2, msk, 16));
    }
    if (sub == 0) {
        float deg = (float)(send - sbeg);
        if (send == sbeg) { m0 = 0.f; m1 = 0.f; m2 = 0.f; }
        float inv = 1.f / fmaxf(deg, 1.f);
        int b = batch[n];
        float* o = nred + (size_t)n * 12;
        o[0] = s0; o[1] = s1; o[2] = s2;
        o[3] = m0; o[4] = m1; o[5] = m2;
        o[6] = s0 * inv; o[7] = s1 * inv; o[8] = s2 * inv;
        o[9] = u[b * 2 + 0]; o[10] = u[b * 2 + 1];
    }
}

// ---------------- node MLP: wave-per-node, weight-stationary ----------------
// Each lane holds W-rows (lane) and (lane+64) of the [128][28] table.
// Inputs per node arrive via uniform scalar loads (SGPRs).
#define NMLP_BLOCKS 1024
#define NMLP_WAVES (NMLP_BLOCKS * 4)
__global__ __launch_bounds__(256, 4) void nodemlp_kernel(
    const float* x_in, const float* __restrict__ nred,
    const float* __restrict__ wt, const float* __restrict__ b2,
    float* x_out)
{
    int lane = threadIdx.x & 63;
    int wid = (blockIdx.x * 256 + threadIdx.x) >> 6;

    const float* ra = wt + lane * 28;
    const float* rb = wt + (lane + 64) * 28;
    float a0 = ra[0], a1 = ra[1], a2 = ra[2], a3 = ra[3], a4 = ra[4], a5 = ra[5],
          a6 = ra[6], a7 = ra[7], a8 = ra[8], a9 = ra[9], a10 = ra[10], a11 = ra[11],
          a12 = ra[12], a13 = ra[13], a14 = ra[14], a15 = ra[15], a16 = ra[16], a17 = ra[17],
          ab = ra[18], p0 = ra[19], p1 = ra[20], p2 = ra[21], p3 = ra[22], p4 = ra[23],
          p5 = ra[24], p6 = ra[25];
    float b0 = rb[0], b1 = rb[1], b2_ = rb[2], b3 = rb[3], b4 = rb[4], b5 = rb[5],
          b6 = rb[6], b7 = rb[7], b8 = rb[8], b9 = rb[9], b10 = rb[10], b11 = rb[11],
          b12 = rb[12], b13 = rb[13], b14 = rb[14], b15 = rb[15], b16 = rb[16], b17 = rb[17],
          bb = rb[18], q0 = rb[19], q1 = rb[20], q2 = rb[21], q3 = rb[22], q4 = rb[23],
          q5 = rb[24], q6 = rb[25];

    asm volatile("" : "+v"(a0), "+v"(a1), "+v"(a2), "+v"(a3), "+v"(a4), "+v"(a5),
                      "+v"(a6), "+v"(a7), "+v"(a8), "+v"(a9), "+v"(a10), "+v"(a11),
                      "+v"(a12), "+v"(a13), "+v"(a14), "+v"(a15), "+v"(a16), "+v"(a17),
                      "+v"(ab), "+v"(p0), "+v"(p1), "+v"(p2), "+v"(p3), "+v"(p4),
                      "+v"(p5), "+v"(p6));
    asm volatile("" : "+v"(b0), "+v"(b1), "+v"(b2_), "+v"(b3), "+v"(b4), "+v"(b5),
                      "+v"(b6), "+v"(b7), "+v"(b8), "+v"(b9), "+v"(b10), "+v"(b11),
                      "+v"(b12), "+v"(b13), "+v"(b14), "+v"(b15), "+v"(b16), "+v"(b17),
                      "+v"(bb), "+v"(q0), "+v"(q1), "+v"(q2), "+v"(q3), "+v"(q4),
                      "+v"(q5), "+v"(q6));

    float B0 = b2[0], B1 = b2[1], B2 = b2[2], B3 = b2[3], B4 = b2[4], B5 = b2[5], B6 = b2[6];

    const int nper = (NN + NMLP_WAVES - 1) / NMLP_WAVES;   // 25
    int n0 = wid * nper;
    int n1 = n0 + nper; if (n1 > NN) n1 = NN;

    for (int n = n0; n < n1; ++n) {
        int nu = __builtin_amdgcn_readfirstlane(n);
        const float* xp = x_in + (size_t)nu * 7;
        const float* rp = nred + (size_t)nu * 12;
        float i0 = xp[0], i1 = xp[1], i2 = xp[2], i3 = xp[3], i4 = xp[4], i5 = xp[5], i6 = xp[6];
        float s0 = rp[0], s1 = rp[1], s2 = rp[2];
        float m0 = rp[3], m1 = rp[4], m2 = rp[5];
        float e0 = rp[6], e1 = rp[7], e2 = rp[8];
        float u0 = rp[9], u1 = rp[10];

        float ha = ab, hb = bb;
        ha += i0 * a0;  hb += i0 * b0;
        ha += i1 * a1;  hb += i1 * b1;
        ha += i2 * a2;  hb += i2 * b2_;
        ha += i3 * a3;  hb += i3 * b3;
        ha += i4 * a4;  hb += i4 * b4;
        ha += i5 * a5;  hb += i5 * b5;
        ha += i6 * a6;  hb += i6 * b6;
        ha += s0 * a7;  hb += s0 * b7;
        ha += s1 * a8;  hb += s1 * b8;
        ha += s2 * a9;  hb += s2 * b9;
        ha += m0 * a10; hb += m0 * b10;
        ha += m1 * a11; hb += m1 * b11;
        ha += m2 * a12; hb += m2 * b12;
        ha += e0 * a13; hb += e0 * b13;
        ha += e1 * a14; hb += e1 * b14;
        ha += e2 * a15; hb += e2 * b15;
        ha += u0 * a16; hb += u0 * b16;
        ha += u1 * a17; hb += u1 * b17;
        ha = fmaxf(ha, 0.f); hb = fmaxf(hb, 0.f);

        float c0 = ha * p0 + hb * q0;
        float c1 = ha * p1 + hb * q1;
        float c2 = ha * p2 + hb * q2;
        float c3 = ha * p3 + hb * q3;
        float c4 = ha * p4 + hb * q4;
        float c5 = ha * p5 + hb * q5;
        float c6 = ha * p6 + hb * q6;
        #pragma unroll
        for (int msk = 1; msk < 64; msk <<= 1) {
            c0 += __shfl_xor(c0, msk);
            c1 += __shfl_xor(c1, msk);
            c2 += __shfl_xor(c2, msk);
            c3 += __shfl_xor(c3, msk);
            c4 += __shfl_xor(c4, msk);
            c5 += __shfl_xor(c5, msk);
            c6 += __shfl_xor(c6, msk);
        }
        float o = c0 + B0;
        if (lane == 1) o = c1 + B1;
        if (lane == 2) o = c2 + B2;
        if (lane == 3) o = c3 + B3;
        if (lane == 4) o = c4 + B4;
        if (lane == 5) o = c5 + B5;
        if (lane == 6) o = c6 + B6;
        if (lane < 7) x_out[(size_t)nu * 7 + lane] = o;
    }
}

// ---------------- fused graph pool + output head (block per graph) ----------
__global__ __launch_bounds__(256) void pool_head_kernel(
    const float* __restrict__ x, const int* __restrict__ gstart,
    const float* __restrict__ u,
    const float* __restrict__ oW1, const float* __restrict__ ob1,
    const float* __restrict__ oW2, const float* __restrict__ ob2,
    const float* __restrict__ oW3, const float* __restrict__ ob3,
    const float* __restrict__ oW4, const float* __restrict__ ob4,
    float* __restrict__ out)
{
    int g = blockIdx.x, tid = threadIdx.x;
    int lane = tid & 63, wv = tid >> 6;
    int gs = gstart[g], ge = gstart[g + 1];

    float s0 = 0.f, s1 = 0.f, s2 = 0.f, s3 = 0.f, s4 = 0.f, s5 = 0.f, s6 = 0.f;
    float m0 = -__builtin_inff(), m1 = m0, m2 = m0, m3 = m0, m4 = m0, m5 = m0, m6 = m0;
    for (int n = gs + tid; n < ge; n += 256) {
        const float* xp = x + (size_t)n * 7;
        float v0 = xp[0], v1 = xp[1], v2 = xp[2], v3 = xp[3], v4 = xp[4], v5 = xp[5], v6 = xp[6];
        s0 += v0; s1 += v1; s2 += v2; s3 += v3; s4 += v4; s5 += v5; s6 += v6;
        m0 = fmaxf(m0, v0); m1 = fmaxf(m1, v1); m2 = fmaxf(m2, v2); m3 = fmaxf(m3, v3);
        m4 = fmaxf(m4, v4); m5 = fmaxf(m5, v5); m6 = fmaxf(m6, v6);
    }
    #pragma unroll
    for (int msk = 1; msk < 64; msk <<= 1) {
        s0 += __shfl_xor(s0, msk); s1 += __shfl_xor(s1, msk); s2 += __shfl_xor(s2, msk);
        s3 += __shfl_xor(s3, msk); s4 += __shfl_xor(s4, msk); s5 += __shfl_xor(s5, msk);
        s6 += __shfl_xor(s6, msk);
        m0 = fmaxf(m0, __shfl_xor(m0, msk)); m1 = fmaxf(m1, __shfl_xor(m1, msk));
        m2 = fmaxf(m2, __shfl_xor(m2, msk)); m3 = fmaxf(m3, __shfl_xor(m3, msk));
        m4 = fmaxf(m4, __shfl_xor(m4, msk)); m5 = fmaxf(m5, __shfl_xor(m5, msk));
        m6 = fmaxf(m6, __shfl_xor(m6, msk));
    }
    __shared__ float red[4][14];
    __shared__ float hin[23];
    __shared__ float ha[128];
    __shared__ float hbuf[128];
    if (lane == 0) {
        red[wv][0] = s0; red[wv][1] = s1; red[wv][2] = s2; red[wv][3] = s3;
        red[wv][4] = s4; red[wv][5] = s5; red[wv][6] = s6;
        red[wv][7] = m0; red[wv][8] = m1; red[wv][9] = m2; red[wv][10] = m3;
        red[wv][11] = m4; red[wv][12] = m5; red[wv][13] = m6;
    }
    __syncthreads();
    if (tid < 7) {
        float S = red[0][tid] + red[1][tid] + red[2][tid] + red[3][tid];
        float M = fmaxf(fmaxf(red[0][7 + tid], red[1][7 + tid]),
                        fmaxf(red[2][7 + tid], red[3][7 + tid]));
        float cntf = (float)(ge - gs);
        if (ge == gs) M = 0.f;
        hin[tid] = S;
        hin[7 + tid] = S / fmaxf(cntf, 1.f);
        hin[14 + tid] = M;
    }
    if (tid < 2) hin[21 + tid] = u[g * 2 + tid];
    __syncthreads();

    float h = 0.f;
    if (tid < 128) {
        h = ob1[tid];
        for (int i = 0; i < 23; ++i) h += hin[i] * oW1[i * 128 + tid];
        ha[tid] = fmaxf(h, 0.f);
    }
    __syncthreads();
    if (tid < 128) {
        h = ob2[tid];
        for (int i = 0; i < 128; ++i) h += ha[i] * oW2[i * 128 + tid];
        hbuf[tid] = fmaxf(h, 0.f);
    }
    __syncthreads();
    if (tid < 128) {
        h = ob3[tid];
        for (int i = 0; i < 128; ++i) h += hbuf[i] * oW3[i * 128 + tid];
        ha[tid] = fmaxf(h, 0.f) * oW4[tid];
    }
    __syncthreads();
    if (tid == 0) {
        float acc = ob4[0];
        for (int i = 0; i < 128; ++i) acc += ha[i];
        out[g] = acc;
    }
}

extern "C" void kernel_launch(void* const* d_in, const int* in_sizes, int n_in,
                              void* d_out, int out_size, void* d_ws, size_t ws_size,
                              hipStream_t stream) {
    const float* x         = (const float*)d_in[0];
    const float* edge_attr = (const float*)d_in[1];
    const float* u         = (const float*)d_in[2];
    const float* eW1 = (const float*)d_in[3];
    const float* eb1 = (const float*)d_in[4];
    const float* eW2 = (const float*)d_in[5];
    const float* eb2 = (const float*)d_in[6];
    const float* nW1 = (const float*)d_in[7];
    const float* nb1 = (const float*)d_in[8];
    const float* nW2 = (const float*)d_in[9];
    const float* nb2 = (const float*)d_in[10];
    const float* oW1 = (const float*)d_in[11];
    const float* ob1 = (const float*)d_in[12];
    const float* oW2 = (const float*)d_in[13];
    const float* ob2 = (const float*)d_in[14];
    const float* oW3 = (const float*)d_in[15];
    const float* ob3 = (const float*)d_in[16];
    const float* oW4 = (const float*)d_in[17];
    const float* ob4 = (const float*)d_in[18];
    const int* edge_index = (const int*)d_in[19];
    const int* batch      = (const int*)d_in[20];
    const int* row = edge_index;
    const int* col = edge_index + NE;

    // workspace layout
    float* ws        = (float*)d_ws;
    float* eab       = ws;                                  // E*3   (19.2 MB)
    float* ws_x      = eab + (size_t)NE * 3;                // N*7   (2.8 MB)
    int2*  rc        = (int2*)(ws_x + (size_t)NN * 7);      // E     (12.8 MB)
    float* nred      = (float*)(rc + (size_t)NE);           // N*12  (4.8 MB)
    unsigned* cnt    = (unsigned*)(nred + (size_t)NN * 12); // N
    unsigned* gdeg   = cnt + NN;                            // 256
    unsigned* startv = gdeg + 256;                          // N+1
    unsigned* cursor = startv + NN + 1;                     // N
    unsigned* bsum   = cursor + NN;                         // 512
    unsigned* boff   = bsum + 512;                          // 512
    int* gstart      = (int*)(boff + 512);                  // 257
    float* ewt       = (float*)(gstart + 260);              // 2*128*24
    float* nwt       = ewt + 2 * 128 * 24;                  // 2*128*28

    dim3 b256(256);
    dim3 ge_(NE / 256);       // 6250, exact
    dim3 gn(NB);              // 391

    // zero cnt + gdeg (adjacent)
    zero_kernel<<<(NN + 256 + 255) / 256, b256, 0, stream>>>((float*)cnt, NN + 256);

    // CSR + graph-range build
    count_kernel<<<ge_, b256, 0, stream>>>(col, cnt);
    gdeg_kernel<<<gn, b256, 0, stream>>>(batch, gdeg);
    bsum_kernel<<<gn, b256, 0, stream>>>(cnt, bsum);
    bscan_kernel<<<1, 512, 0, stream>>>(bsum, boff);
    start_kernel<<<gn, b256, 0, stream>>>(cnt, boff, startv, cursor);
    gscan_kernel<<<1, 256, 0, stream>>>(gdeg, gstart);
    scatter_kernel<<<ge_, b256, 0, stream>>>(row, col, edge_attr, cursor, rc, eab);

    // weight prep
    {
        int t = 2 * 128 * 24 + 2 * 128 * 28;
        prep_kernel<<<(t + 255) / 256, b256, 0, stream>>>(eW1, eb1, eW2, nW1, nb1, nW2, ewt, nwt);
    }

    dim3 gr((NN * 16 + 255) / 256);   // 6250 blocks for reduce

    // ---- layer 0 ----
    edge_kernel<<<ge_, b256, 0, stream>>>(x, eab, rc, ewt, eb2);
    reduce_kernel<<<gr, b256, 0, stream>>>(eab, startv, u, batch, nred);
    nodemlp_kernel<<<NMLP_BLOCKS, b256, 0, stream>>>(x, nred, nwt, nb2, ws_x);

    // ---- layer 1 ----
    edge_kernel<<<ge_, b256, 0, stream>>>(ws_x, eab, rc, ewt + 128 * 24, eb2 + 3);
    reduce_kernel<<<gr, b256, 0, stream>>>(eab, startv, u, batch, nred);
    nodemlp_kernel<<<NMLP_BLOCKS, b256, 0, stream>>>(ws_x, nred, nwt + 128 * 28, nb2 + 7, ws_x);

    // ---- fused pool + head ----
    pool_head_kernel<<<NG, b256, 0, stream>>>(ws_x, gstart, u,
        oW1, ob1, oW2, ob2, oW3, ob3, oW4, ob4, (float*)d_out);
}

// Round 6
// 695.722 us; speedup vs baseline: 2.0050x; 1.1467x over previous
//
#include <hip/hip_runtime.h>

#define NN 100000
#define NE 1600000
#define NG 256
#define NB 391   // ceil(NN/256)

__global__ __launch_bounds__(256) void zero_kernel(float* __restrict__ p, int n) {
    int i = blockIdx.x * 256 + threadIdx.x;
    if (i < n) p[i] = 0.f;
}

// ---------------- CSR build ----------------
__global__ __launch_bounds__(256) void count_kernel(
    const int* __restrict__ col, unsigned* __restrict__ cnt) {
    int e = blockIdx.x * 256 + threadIdx.x;       // grid covers NE exactly
    atomicAdd(&cnt[col[e]], 1u);
}

__global__ __launch_bounds__(256) void gdeg_kernel(
    const int* __restrict__ batch, unsigned* __restrict__ gdeg) {
    int n = blockIdx.x * 256 + threadIdx.x;
    if (n < NN) atomicAdd(&gdeg[batch[n]], 1u);
}

__global__ __launch_bounds__(256) void bsum_kernel(
    const unsigned* __restrict__ cnt, unsigned* __restrict__ bsum) {
    __shared__ unsigned sm[256];
    int i = blockIdx.x * 256 + threadIdx.x;
    sm[threadIdx.x] = (i < NN) ? cnt[i] : 0u;
    __syncthreads();
    for (int s = 128; s > 0; s >>= 1) {
        if (threadIdx.x < s) sm[threadIdx.x] += sm[threadIdx.x + s];
        __syncthreads();
    }
    if (threadIdx.x == 0) bsum[blockIdx.x] = sm[0];
}

__global__ __launch_bounds__(512) void bscan_kernel(
    const unsigned* __restrict__ bsum, unsigned* __restrict__ boff) {
    __shared__ unsigned a[512], b[512];
    int t = threadIdx.x;
    a[t] = (t < NB) ? bsum[t] : 0u;
    __syncthreads();
    unsigned* src = a; unsigned* dst = b;
    for (int off = 1; off < 512; off <<= 1) {
        unsigned v = src[t];
        if (t >= off) v += src[t - off];
        dst[t] = v;
        __syncthreads();
        unsigned* tmp = src; src = dst; dst = tmp;
    }
    if (t < NB) boff[t] = (t == 0) ? 0u : src[t - 1];
}

__global__ __launch_bounds__(256) void start_kernel(
    const unsigned* __restrict__ cnt, const unsigned* __restrict__ boff,
    unsigned* __restrict__ start, unsigned* __restrict__ cursor) {
    __shared__ unsigned a[256], b[256];
    int t = threadIdx.x;
    int i = blockIdx.x * 256 + t;
    unsigned v = (i < NN) ? cnt[i] : 0u;
    a[t] = v;
    __syncthreads();
    unsigned* src = a; unsigned* dst = b;
    for (int off = 1; off < 256; off <<= 1) {
        unsigned x = src[t];
        if (t >= off) x += src[t - off];
        dst[t] = x;
        __syncthreads();
        unsigned* tmp = src; src = dst; dst = tmp;
    }
    unsigned excl = src[t] - v;
    unsigned st = boff[blockIdx.x] + excl;
    if (i < NN) {
        start[i] = st;
        cursor[i] = st;
        if (i == NN - 1) start[NN] = st + v;
    }
}

__global__ __launch_bounds__(256) void gscan_kernel(
    const unsigned* __restrict__ gdeg, int* __restrict__ gstart) {
    __shared__ unsigned a[256], b[256];
    int t = threadIdx.x;
    a[t] = gdeg[t];
    __syncthreads();
    unsigned* src = a; unsigned* dst = b;
    for (int off = 1; off < 256; off <<= 1) {   // 8 iters -> src == a at end
        unsigned v = src[t];
        if (t >= off) v += src[t - off];
        dst[t] = v;
        __syncthreads();
        unsigned* tmp = src; src = dst; dst = tmp;
    }
    if (t == 0) gstart[0] = 0;
    gstart[t + 1] = (int)src[t];
}

__global__ __launch_bounds__(256) void scatter_kernel(
    const int* __restrict__ row, const int* __restrict__ col,
    const float* __restrict__ ea,
    unsigned* __restrict__ cursor, int2* __restrict__ rc, float* __restrict__ eab) {
    int e = blockIdx.x * 256 + threadIdx.x;       // grid covers NE exactly
    int c = col[e];
    unsigned t = atomicAdd(&cursor[c], 1u);
    rc[t] = make_int2(row[e], c);
    eab[(size_t)t * 3 + 0] = ea[(size_t)e * 3 + 0];
    eab[(size_t)t * 3 + 1] = ea[(size_t)e * 3 + 1];
    eab[(size_t)t * 3 + 2] = ea[(size_t)e * 3 + 2];
}

// ---------------- weight prep (padded rows) ----------------
//   ewt: 2 x 128 x 24  [W1[0..16][j], b1[j], W2[j][0..2], pad x3]
//   nwt: 2 x 128 x 28  [W1[0..17][j], b1[j], W2[j][0..6], pad x2]
__global__ __launch_bounds__(256) void prep_kernel(
    const float* __restrict__ eW1, const float* __restrict__ eb1, const float* __restrict__ eW2,
    const float* __restrict__ nW1, const float* __restrict__ nb1, const float* __restrict__ nW2,
    float* __restrict__ ewt, float* __restrict__ nwt)
{
    int t = blockIdx.x * 256 + threadIdx.x;
    const int ESZ = 2 * 128 * 24;
    const int NSZ = 2 * 128 * 28;
    if (t < ESZ) {
        int l = t / (128 * 24), rest = t % (128 * 24), j = rest / 24, i = rest % 24;
        float v = 0.f;
        if (i < 17)       v = eW1[l * 17 * 128 + i * 128 + j];
        else if (i == 17) v = eb1[l * 128 + j];
        else if (i < 21)  v = eW2[l * 128 * 3 + j * 3 + (i - 18)];
        ewt[t] = v;
    } else if (t < ESZ + NSZ) {
        int q = t - ESZ;
        int l = q / (128 * 28), rest = q % (128 * 28), j = rest / 28, i = rest % 28;
        float v = 0.f;
        if (i < 18)       v = nW1[l * 18 * 128 + i * 128 + j];
        else if (i == 18) v = nb1[l * 128 + j];
        else if (i < 26)  v = nW2[l * 128 * 7 + j * 7 + (i - 19)];
        nwt[q] = v;
    }
}

// ---------------- edge MLP: 2 edges/thread, scalar weights, unroll 4 --------
// grid*256*2 == NE exactly (3125*512 = 1600000) -> no bounds checks.
__global__ __launch_bounds__(256) void edge_kernel(
    const float* __restrict__ x, float* eab,
    const int2* __restrict__ rc,
    const float* __restrict__ wt, const float* __restrict__ b2)
{
    int tA = blockIdx.x * 512 + threadIdx.x;
    int tB = tA + 256;
    int2 pA = rc[tA], pB = rc[tB];
    const float* xrA = x + (size_t)pA.x * 7;
    const float* xcA = x + (size_t)pA.y * 7;
    const float* xrB = x + (size_t)pB.x * 7;
    const float* xcB = x + (size_t)pB.y * 7;

    float A0 = xrA[0], A1 = xrA[1], A2 = xrA[2], A3 = xrA[3], A4 = xrA[4], A5 = xrA[5], A6 = xrA[6];
    float A7 = xcA[0], A8 = xcA[1], A9 = xcA[2], A10 = xcA[3], A11 = xcA[4], A12 = xcA[5], A13 = xcA[6];
    float A14 = eab[(size_t)tA * 3 + 0], A15 = eab[(size_t)tA * 3 + 1], A16 = eab[(size_t)tA * 3 + 2];
    float B0 = xrB[0], B1 = xrB[1], B2 = xrB[2], B3 = xrB[3], B4 = xrB[4], B5 = xrB[5], B6 = xrB[6];
    float B7 = xcB[0], B8 = xcB[1], B9 = xcB[2], B10 = xcB[3], B11 = xcB[4], B12 = xcB[5], B13 = xcB[6];
    float B14 = eab[(size_t)tB * 3 + 0], B15 = eab[(size_t)tB * 3 + 1], B16 = eab[(size_t)tB * 3 + 2];

    // pin gathers into VGPRs: loads cannot be sunk/rematerialized into the loop
    asm volatile("" : "+v"(A0), "+v"(A1), "+v"(A2), "+v"(A3), "+v"(A4), "+v"(A5),
                      "+v"(A6), "+v"(A7), "+v"(A8), "+v"(A9), "+v"(A10), "+v"(A11),
                      "+v"(A12), "+v"(A13), "+v"(A14), "+v"(A15), "+v"(A16));
    asm volatile("" : "+v"(B0), "+v"(B1), "+v"(B2), "+v"(B3), "+v"(B4), "+v"(B5),
                      "+v"(B6), "+v"(B7), "+v"(B8), "+v"(B9), "+v"(B10), "+v"(B11),
                      "+v"(B12), "+v"(B13), "+v"(B14), "+v"(B15), "+v"(B16));

    float aA0 = 0.f, aA1 = 0.f, aA2 = 0.f;
    float aB0 = 0.f, aB1 = 0.f, aB2 = 0.f;

    #pragma unroll 4
    for (int j = 0; j < 128; ++j) {
        const float* wr = wt + __builtin_amdgcn_readfirstlane(j * 24);
        float w[21];
        #pragma unroll
        for (int i = 0; i < 21; ++i) w[i] = wr[i];
        float hA0 = w[17], hA1 = 0.f, hB0 = w[17], hB1 = 0.f;
        hA0 += A0 * w[0];   hA1 += A1 * w[1];   hB0 += B0 * w[0];   hB1 += B1 * w[1];
        hA0 += A2 * w[2];   hA1 += A3 * w[3];   hB0 += B2 * w[2];   hB1 += B3 * w[3];
        hA0 += A4 * w[4];   hA1 += A5 * w[5];   hB0 += B4 * w[4];   hB1 += B5 * w[5];
        hA0 += A6 * w[6];   hA1 += A7 * w[7];   hB0 += B6 * w[6];   hB1 += B7 * w[7];
        hA0 += A8 * w[8];   hA1 += A9 * w[9];   hB0 += B8 * w[8];   hB1 += B9 * w[9];
        hA0 += A10 * w[10]; hA1 += A11 * w[11]; hB0 += B10 * w[10]; hB1 += B11 * w[11];
        hA0 += A12 * w[12]; hA1 += A13 * w[13]; hB0 += B12 * w[12]; hB1 += B13 * w[13];
        hA0 += A14 * w[14]; hA1 += A15 * w[15]; hB0 += B14 * w[14]; hB1 += B15 * w[15];
        hA0 += A16 * w[16];                     hB0 += B16 * w[16];
        float hA = fmaxf(hA0 + hA1, 0.f);
        float hB = fmaxf(hB0 + hB1, 0.f);
        aA0 += hA * w[18]; aB0 += hB * w[18];
        aA1 += hA * w[19]; aB1 += hB * w[19];
        aA2 += hA * w[20]; aB2 += hB * w[20];
    }

    float bb0 = b2[0], bb1 = b2[1], bb2 = b2[2];
    eab[(size_t)tA * 3 + 0] = aA0 + bb0;
    eab[(size_t)tA * 3 + 1] = aA1 + bb1;
    eab[(size_t)tA * 3 + 2] = aA2 + bb2;
    eab[(size_t)tB * 3 + 0] = aB0 + bb0;
    eab[(size_t)tB * 3 + 1] = aB1 + bb1;
    eab[(size_t)tB * 3 + 2] = aB2 + bb2;
}

// ---------------- segment reduce: 16 lanes per node ----------------
// writes nred[n][12] = [s0,s1,s2, m0,m1,m2, mean0,mean1,mean2, u0,u1, pad]
__global__ __launch_bounds__(256) void reduce_kernel(
    const float* __restrict__ eab, const unsigned* __restrict__ start,
    const float* __restrict__ u, const int* __restrict__ batch,
    float* __restrict__ nred)
{
    int gid = blockIdx.x * 256 + threadIdx.x;
    int n = gid >> 4, sub = gid & 15;
    if (n >= NN) return;
    unsigned sbeg = start[n], send = start[n + 1];

    float s0 = 0.f, s1 = 0.f, s2 = 0.f;
    float m0 = -__builtin_inff(), m1 = -__builtin_inff(), m2 = -__builtin_inff();
    for (unsigned k = sbeg + sub; k < send; k += 16) {
        float v0 = eab[(size_t)k * 3 + 0];
        float v1 = eab[(size_t)k * 3 + 1];
        float v2 = eab[(size_t)k * 3 + 2];
        s0 += v0; s1 += v1; s2 += v2;
        m0 = fmaxf(m0, v0); m1 = fmaxf(m1, v1); m2 = fmaxf(m2, v2);
    }
    #pragma unroll
    for (int msk = 1; msk < 16; msk <<= 1) {
        s0 += __shfl_xor(s0, msk, 16);
        s1 += __shfl_xor(s1, msk, 16);
        s2 += __shfl_xor(s2, msk, 16);
        m0 = fmaxf(m0, __shfl_xor(m0, msk, 16));
        m1 = fmaxf(m1, __shfl_xor(m1, msk, 16));
        m2 = fmaxf(m2, __shfl_xor(m2, msk, 16));
    }
    if (sub == 0) {
        float deg = (float)(send - sbeg);
        if (send == sbeg) { m0 = 0.f; m1 = 0.f; m2 = 0.f; }
        float inv = 1.f / fmaxf(deg, 1.f);
        int b = batch[n];
        float* o = nred + (size_t)n * 12;
        o[0] = s0; o[1] = s1; o[2] = s2;
        o[3] = m0; o[4] = m1; o[5] = m2;
        o[6] = s0 * inv; o[7] = s1 * inv; o[8] = s2 * inv;
        o[9] = u[b * 2 + 0]; o[10] = u[b * 2 + 1];
    }
}

// ---------------- node MLP: wave-per-node, weight-stationary ----------------
#define NMLP_BLOCKS 1024
#define NMLP_WAVES (NMLP_BLOCKS * 4)
__global__ __launch_bounds__(256, 4) void nodemlp_kernel(
    const float* x_in, const float* __restrict__ nred,
    const float* __restrict__ wt, const float* __restrict__ b2,
    float* x_out)
{
    int lane = threadIdx.x & 63;
    int wid = (blockIdx.x * 256 + threadIdx.x) >> 6;

    const float* ra = wt + lane * 28;
    const float* rb = wt + (lane + 64) * 28;
    float a0 = ra[0], a1 = ra[1], a2 = ra[2], a3 = ra[3], a4 = ra[4], a5 = ra[5],
          a6 = ra[6], a7 = ra[7], a8 = ra[8], a9 = ra[9], a10 = ra[10], a11 = ra[11],
          a12 = ra[12], a13 = ra[13], a14 = ra[14], a15 = ra[15], a16 = ra[16], a17 = ra[17],
          ab = ra[18], p0 = ra[19], p1 = ra[20], p2 = ra[21], p3 = ra[22], p4 = ra[23],
          p5 = ra[24], p6 = ra[25];
    float b0 = rb[0], b1 = rb[1], b2_ = rb[2], b3 = rb[3], b4 = rb[4], b5 = rb[5],
          b6 = rb[6], b7 = rb[7], b8 = rb[8], b9 = rb[9], b10 = rb[10], b11 = rb[11],
          b12 = rb[12], b13 = rb[13], b14 = rb[14], b15 = rb[15], b16 = rb[16], b17 = rb[17],
          bb = rb[18], q0 = rb[19], q1 = rb[20], q2 = rb[21], q3 = rb[22], q4 = rb[23],
          q5 = rb[24], q6 = rb[25];

    asm volatile("" : "+v"(a0), "+v"(a1), "+v"(a2), "+v"(a3), "+v"(a4), "+v"(a5),
                      "+v"(a6), "+v"(a7), "+v"(a8), "+v"(a9), "+v"(a10), "+v"(a11),
                      "+v"(a12), "+v"(a13), "+v"(a14), "+v"(a15), "+v"(a16), "+v"(a17),
                      "+v"(ab), "+v"(p0), "+v"(p1), "+v"(p2), "+v"(p3), "+v"(p4),
                      "+v"(p5), "+v"(p6));
    asm volatile("" : "+v"(b0), "+v"(b1), "+v"(b2_), "+v"(b3), "+v"(b4), "+v"(b5),
                      "+v"(b6), "+v"(b7), "+v"(b8), "+v"(b9), "+v"(b10), "+v"(b11),
                      "+v"(b12), "+v"(b13), "+v"(b14), "+v"(b15), "+v"(b16), "+v"(b17),
                      "+v"(bb), "+v"(q0), "+v"(q1), "+v"(q2), "+v"(q3), "+v"(q4),
                      "+v"(q5), "+v"(q6));

    float B0 = b2[0], B1 = b2[1], B2 = b2[2], B3 = b2[3], B4 = b2[4], B5 = b2[5], B6 = b2[6];

    const int nper = (NN + NMLP_WAVES - 1) / NMLP_WAVES;   // 25
    int n0 = wid * nper;
    int n1 = n0 + nper; if (n1 > NN) n1 = NN;

    #pragma unroll 2
    for (int n = n0; n < n1; ++n) {
        int nu = __builtin_amdgcn_readfirstlane(n);
        const float* xp = x_in + (size_t)nu * 7;
        const float* rp = nred + (size_t)nu * 12;
        float i0 = xp[0], i1 = xp[1], i2 = xp[2], i3 = xp[3], i4 = xp[4], i5 = xp[5], i6 = xp[6];
        float s0 = rp[0], s1 = rp[1], s2 = rp[2];
        float m0 = rp[3], m1 = rp[4], m2 = rp[5];
        float e0 = rp[6], e1 = rp[7], e2 = rp[8];
        float u0 = rp[9], u1 = rp[10];

        float ha = ab, hb = bb;
        ha += i0 * a0;  hb += i0 * b0;
        ha += i1 * a1;  hb += i1 * b1;
        ha += i2 * a2;  hb += i2 * b2_;
        ha += i3 * a3;  hb += i3 * b3;
        ha += i4 * a4;  hb += i4 * b4;
        ha += i5 * a5;  hb += i5 * b5;
        ha += i6 * a6;  hb += i6 * b6;
        ha += s0 * a7;  hb += s0 * b7;
        ha += s1 * a8;  hb += s1 * b8;
        ha += s2 * a9;  hb += s2 * b9;
        ha += m0 * a10; hb += m0 * b10;
        ha += m1 * a11; hb += m1 * b11;
        ha += m2 * a12; hb += m2 * b12;
        ha += e0 * a13; hb += e0 * b13;
        ha += e1 * a14; hb += e1 * b14;
        ha += e2 * a15; hb += e2 * b15;
        ha += u0 * a16; hb += u0 * b16;
        ha += u1 * a17; hb += u1 * b17;
        ha = fmaxf(ha, 0.f); hb = fmaxf(hb, 0.f);

        float c0 = ha * p0 + hb * q0;
        float c1 = ha * p1 + hb * q1;
        float c2 = ha * p2 + hb * q2;
        float c3 = ha * p3 + hb * q3;
        float c4 = ha * p4 + hb * q4;
        float c5 = ha * p5 + hb * q5;
        float c6 = ha * p6 + hb * q6;
        #pragma unroll
        for (int msk = 1; msk < 64; msk <<= 1) {
            c0 += __shfl_xor(c0, msk);
            c1 += __shfl_xor(c1, msk);
            c2 += __shfl_xor(c2, msk);
            c3 += __shfl_xor(c3, msk);
            c4 += __shfl_xor(c4, msk);
            c5 += __shfl_xor(c5, msk);
            c6 += __shfl_xor(c6, msk);
        }
        float o = c0 + B0;
        if (lane == 1) o = c1 + B1;
        if (lane == 2) o = c2 + B2;
        if (lane == 3) o = c3 + B3;
        if (lane == 4) o = c4 + B4;
        if (lane == 5) o = c5 + B5;
        if (lane == 6) o = c6 + B6;
        if (lane < 7) x_out[(size_t)nu * 7 + lane] = o;
    }
}

// ---------------- fused graph pool + output head (block per graph) ----------
__global__ __launch_bounds__(256) void pool_head_kernel(
    const float* __restrict__ x, const int* __restrict__ gstart,
    const float* __restrict__ u,
    const float* __restrict__ oW1, const float* __restrict__ ob1,
    const float* __restrict__ oW2, const float* __restrict__ ob2,
    const float* __restrict__ oW3, const float* __restrict__ ob3,
    const float* __restrict__ oW4, const float* __restrict__ ob4,
    float* __restrict__ out)
{
    int g = blockIdx.x, tid = threadIdx.x;
    int lane = tid & 63, wv = tid >> 6;
    int gs = gstart[g], ge = gstart[g + 1];

    float s0 = 0.f, s1 = 0.f, s2 = 0.f, s3 = 0.f, s4 = 0.f, s5 = 0.f, s6 = 0.f;
    float m0 = -__builtin_inff(), m1 = m0, m2 = m0, m3 = m0, m4 = m0, m5 = m0, m6 = m0;
    for (int n = gs + tid; n < ge; n += 256) {
        const float* xp = x + (size_t)n * 7;
        float v0 = xp[0], v1 = xp[1], v2 = xp[2], v3 = xp[3], v4 = xp[4], v5 = xp[5], v6 = xp[6];
        s0 += v0; s1 += v1; s2 += v2; s3 += v3; s4 += v4; s5 += v5; s6 += v6;
        m0 = fmaxf(m0, v0); m1 = fmaxf(m1, v1); m2 = fmaxf(m2, v2); m3 = fmaxf(m3, v3);
        m4 = fmaxf(m4, v4); m5 = fmaxf(m5, v5); m6 = fmaxf(m6, v6);
    }
    #pragma unroll
    for (int msk = 1; msk < 64; msk <<= 1) {
        s0 += __shfl_xor(s0, msk); s1 += __shfl_xor(s1, msk); s2 += __shfl_xor(s2, msk);
        s3 += __shfl_xor(s3, msk); s4 += __shfl_xor(s4, msk); s5 += __shfl_xor(s5, msk);
        s6 += __shfl_xor(s6, msk);
        m0 = fmaxf(m0, __shfl_xor(m0, msk)); m1 = fmaxf(m1, __shfl_xor(m1, msk));
        m2 = fmaxf(m2, __shfl_xor(m2, msk)); m3 = fmaxf(m3, __shfl_xor(m3, msk));
        m4 = fmaxf(m4, __shfl_xor(m4, msk)); m5 = fmaxf(m5, __shfl_xor(m5, msk));
        m6 = fmaxf(m6, __shfl_xor(m6, msk));
    }
    __shared__ float red[4][14];
    __shared__ float hin[23];
    __shared__ float ha[128];
    __shared__ float hbuf[128];
    if (lane == 0) {
        red[wv][0] = s0; red[wv][1] = s1; red[wv][2] = s2; red[wv][3] = s3;
        red[wv][4] = s4; red[wv][5] = s5; red[wv][6] = s6;
        red[wv][7] = m0; red[wv][8] = m1; red[wv][9] = m2; red[wv][10] = m3;
        red[wv][11] = m4; red[wv][12] = m5; red[wv][13] = m6;
    }
    __syncthreads();
    if (tid < 7) {
        float S = red[0][tid] + red[1][tid] + red[2][tid] + red[3][tid];
        float M = fmaxf(fmaxf(red[0][7 + tid], red[1][7 + tid]),
                        fmaxf(red[2][7 + tid], red[3][7 + tid]));
        float cntf = (float)(ge - gs);
        if (ge == gs) M = 0.f;
        hin[tid] = S;
        hin[7 + tid] = S / fmaxf(cntf, 1.f);
        hin[14 + tid] = M;
    }
    if (tid < 2) hin[21 + tid] = u[g * 2 + tid];
    __syncthreads();

    float h = 0.f;
    if (tid < 128) {
        h = ob1[tid];
        for (int i = 0; i < 23; ++i) h += hin[i] * oW1[i * 128 + tid];
        ha[tid] = fmaxf(h, 0.f);
    }
    __syncthreads();
    if (tid < 128) {
        h = ob2[tid];
        for (int i = 0; i < 128; ++i) h += ha[i] * oW2[i * 128 + tid];
        hbuf[tid] = fmaxf(h, 0.f);
    }
    __syncthreads();
    if (tid < 128) {
        h = ob3[tid];
        for (int i = 0; i < 128; ++i) h += hbuf[i] * oW3[i * 128 + tid];
        ha[tid] = fmaxf(h, 0.f) * oW4[tid];
    }
    __syncthreads();
    if (tid == 0) {
        float acc = ob4[0];
        for (int i = 0; i < 128; ++i) acc += ha[i];
        out[g] = acc;
    }
}

extern "C" void kernel_launch(void* const* d_in, const int* in_sizes, int n_in,
                              void* d_out, int out_size, void* d_ws, size_t ws_size,
                              hipStream_t stream) {
    const float* x         = (const float*)d_in[0];
    const float* edge_attr = (const float*)d_in[1];
    const float* u         = (const float*)d_in[2];
    const float* eW1 = (const float*)d_in[3];
    const float* eb1 = (const float*)d_in[4];
    const float* eW2 = (const float*)d_in[5];
    const float* eb2 = (const float*)d_in[6];
    const float* nW1 = (const float*)d_in[7];
    const float* nb1 = (const float*)d_in[8];
    const float* nW2 = (const float*)d_in[9];
    const float* nb2 = (const float*)d_in[10];
    const float* oW1 = (const float*)d_in[11];
    const float* ob1 = (const float*)d_in[12];
    const float* oW2 = (const float*)d_in[13];
    const float* ob2 = (const float*)d_in[14];
    const float* oW3 = (const float*)d_in[15];
    const float* ob3 = (const float*)d_in[16];
    const float* oW4 = (const float*)d_in[17];
    const float* ob4 = (const float*)d_in[18];
    const int* edge_index = (const int*)d_in[19];
    const int* batch      = (const int*)d_in[20];
    const int* row = edge_index;
    const int* col = edge_index + NE;

    // workspace layout
    float* ws        = (float*)d_ws;
    float* eab       = ws;                                  // E*3   (19.2 MB)
    float* ws_x      = eab + (size_t)NE * 3;                // N*7   (2.8 MB)
    int2*  rc        = (int2*)(ws_x + (size_t)NN * 7);      // E     (12.8 MB)
    float* nred      = (float*)(rc + (size_t)NE);           // N*12  (4.8 MB)
    unsigned* cnt    = (unsigned*)(nred + (size_t)NN * 12); // N
    unsigned* gdeg   = cnt + NN;                            // 256
    unsigned* startv = gdeg + 256;                          // N+1
    unsigned* cursor = startv + NN + 1;                     // N
    unsigned* bsum   = cursor + NN;                         // 512
    unsigned* boff   = bsum + 512;                          // 512
    int* gstart      = (int*)(boff + 512);                  // 257
    float* ewt       = (float*)(gstart + 260);              // 2*128*24
    float* nwt       = ewt + 2 * 128 * 24;                  // 2*128*28

    dim3 b256(256);
    dim3 ge_(NE / 256);       // 6250, exact
    dim3 ge2(NE / 512);       // 3125, exact (2 edges/thread)
    dim3 gn(NB);              // 391

    // zero cnt + gdeg (adjacent)
    zero_kernel<<<(NN + 256 + 255) / 256, b256, 0, stream>>>((float*)cnt, NN + 256);

    // CSR + graph-range build
    count_kernel<<<ge_, b256, 0, stream>>>(col, cnt);
    gdeg_kernel<<<gn, b256, 0, stream>>>(batch, gdeg);
    bsum_kernel<<<gn, b256, 0, stream>>>(cnt, bsum);
    bscan_kernel<<<1, 512, 0, stream>>>(bsum, boff);
    start_kernel<<<gn, b256, 0, stream>>>(cnt, boff, startv, cursor);
    gscan_kernel<<<1, 256, 0, stream>>>(gdeg, gstart);
    scatter_kernel<<<ge_, b256, 0, stream>>>(row, col, edge_attr, cursor, rc, eab);

    // weight prep
    {
        int t = 2 * 128 * 24 + 2 * 128 * 28;
        prep_kernel<<<(t + 255) / 256, b256, 0, stream>>>(eW1, eb1, eW2, nW1, nb1, nW2, ewt, nwt);
    }

    dim3 gr((NN * 16 + 255) / 256);   // 6250 blocks for reduce

    // ---- layer 0 ----
    edge_kernel<<<ge2, b256, 0, stream>>>(x, eab, rc, ewt, eb2);
    reduce_kernel<<<gr, b256, 0, stream>>>(eab, startv, u, batch, nred);
    nodemlp_kernel<<<NMLP_BLOCKS, b256, 0, stream>>>(x, nred, nwt, nb2, ws_x);

    // ---- layer 1 ----
    edge_kernel<<<ge2, b256, 0, stream>>>(ws_x, eab, rc, ewt + 128 * 24, eb2 + 3);
    reduce_kernel<<<gr, b256, 0, stream>>>(eab, startv, u, batch, nred);
    nodemlp_kernel<<<NMLP_BLOCKS, b256, 0, stream>>>(ws_x, nred, nwt + 128 * 28, nb2 + 7, ws_x);

    // ---- fused pool + head ----
    pool_head_kernel<<<NG, b256, 0, stream>>>(ws_x, gstart, u,
        oW1, ob1, oW2, ob2, oW3, ob3, oW4, ob4, (float*)d_out);
}

// Round 7
// 534.298 us; speedup vs baseline: 2.6108x; 1.3021x over previous
//
#include <hip/hip_runtime.h>

#define NN 100000
#define NE 1600000
#define NG 256
#define NB 391   // ceil(NN/256)

__global__ __launch_bounds__(256) void zero_kernel(float* __restrict__ p, int n) {
    int i = blockIdx.x * 256 + threadIdx.x;
    if (i < n) p[i] = 0.f;
}

// ---------------- CSR build ----------------
__global__ __launch_bounds__(256) void count_kernel(
    const int* __restrict__ col, unsigned* __restrict__ cnt) {
    int e = blockIdx.x * 256 + threadIdx.x;       // grid covers NE exactly
    atomicAdd(&cnt[col[e]], 1u);
}

// batch is sorted: graph g starts where batch steps past g. No atomics.
__global__ __launch_bounds__(256) void gbound_kernel(
    const int* __restrict__ batch, int* __restrict__ gstart) {
    int n = blockIdx.x * 256 + threadIdx.x;
    if (n >= NN) return;
    int b = batch[n];
    int bp = (n == 0) ? -1 : batch[n - 1];
    for (int g = bp + 1; g <= b; ++g) gstart[g] = n;     // graphs starting at n
    if (n == NN - 1) {
        for (int g = b + 1; g <= NG; ++g) gstart[g] = NN; // tail (incl. gstart[NG])
    }
}

__global__ __launch_bounds__(256) void bsum_kernel(
    const unsigned* __restrict__ cnt, unsigned* __restrict__ bsum) {
    __shared__ unsigned sm[256];
    int i = blockIdx.x * 256 + threadIdx.x;
    sm[threadIdx.x] = (i < NN) ? cnt[i] : 0u;
    __syncthreads();
    for (int s = 128; s > 0; s >>= 1) {
        if (threadIdx.x < s) sm[threadIdx.x] += sm[threadIdx.x + s];
        __syncthreads();
    }
    if (threadIdx.x == 0) bsum[blockIdx.x] = sm[0];
}

__global__ __launch_bounds__(512) void bscan_kernel(
    const unsigned* __restrict__ bsum, unsigned* __restrict__ boff) {
    __shared__ unsigned a[512], b[512];
    int t = threadIdx.x;
    a[t] = (t < NB) ? bsum[t] : 0u;
    __syncthreads();
    unsigned* src = a; unsigned* dst = b;
    for (int off = 1; off < 512; off <<= 1) {
        unsigned v = src[t];
        if (t >= off) v += src[t - off];
        dst[t] = v;
        __syncthreads();
        unsigned* tmp = src; src = dst; dst = tmp;
    }
    if (t < NB) boff[t] = (t == 0) ? 0u : src[t - 1];
}

__global__ __launch_bounds__(256) void start_kernel(
    const unsigned* __restrict__ cnt, const unsigned* __restrict__ boff,
    unsigned* __restrict__ start, unsigned* __restrict__ cursor) {
    __shared__ unsigned a[256], b[256];
    int t = threadIdx.x;
    int i = blockIdx.x * 256 + t;
    unsigned v = (i < NN) ? cnt[i] : 0u;
    a[t] = v;
    __syncthreads();
    unsigned* src = a; unsigned* dst = b;
    for (int off = 1; off < 256; off <<= 1) {
        unsigned x = src[t];
        if (t >= off) x += src[t - off];
        dst[t] = x;
        __syncthreads();
        unsigned* tmp = src; src = dst; dst = tmp;
    }
    unsigned excl = src[t] - v;
    unsigned st = boff[blockIdx.x] + excl;
    if (i < NN) {
        start[i] = st;
        cursor[i] = st;
        if (i == NN - 1) start[NN] = st + v;
    }
}

__global__ __launch_bounds__(256) void scatter_kernel(
    const int* __restrict__ row, const int* __restrict__ col,
    const float* __restrict__ ea,
    unsigned* __restrict__ cursor, int2* __restrict__ rc, float* __restrict__ eab) {
    int e = blockIdx.x * 256 + threadIdx.x;       // grid covers NE exactly
    int c = col[e];
    unsigned t = atomicAdd(&cursor[c], 1u);
    rc[t] = make_int2(row[e], c);
    eab[(size_t)t * 3 + 0] = ea[(size_t)e * 3 + 0];
    eab[(size_t)t * 3 + 1] = ea[(size_t)e * 3 + 1];
    eab[(size_t)t * 3 + 2] = ea[(size_t)e * 3 + 2];
}

// ---------------- weight prep (padded rows) ----------------
//   ewt: 2 x 128 x 24  [W1[0..16][j], b1[j], W2[j][0..2], pad x3]
//   nwt: 2 x 128 x 28  [W1[0..17][j], b1[j], W2[j][0..6], pad x2]
__global__ __launch_bounds__(256) void prep_kernel(
    const float* __restrict__ eW1, const float* __restrict__ eb1, const float* __restrict__ eW2,
    const float* __restrict__ nW1, const float* __restrict__ nb1, const float* __restrict__ nW2,
    float* __restrict__ ewt, float* __restrict__ nwt)
{
    int t = blockIdx.x * 256 + threadIdx.x;
    const int ESZ = 2 * 128 * 24;
    const int NSZ = 2 * 128 * 28;
    if (t < ESZ) {
        int l = t / (128 * 24), rest = t % (128 * 24), j = rest / 24, i = rest % 24;
        float v = 0.f;
        if (i < 17)       v = eW1[l * 17 * 128 + i * 128 + j];
        else if (i == 17) v = eb1[l * 128 + j];
        else if (i < 21)  v = eW2[l * 128 * 3 + j * 3 + (i - 18)];
        ewt[t] = v;
    } else if (t < ESZ + NSZ) {
        int q = t - ESZ;
        int l = q / (128 * 28), rest = q % (128 * 28), j = rest / 28, i = rest % 28;
        float v = 0.f;
        if (i < 18)       v = nW1[l * 18 * 128 + i * 128 + j];
        else if (i == 18) v = nb1[l * 128 + j];
        else if (i < 26)  v = nW2[l * 128 * 7 + j * 7 + (i - 19)];
        nwt[q] = v;
    }
}

// ---------------- edge MLP: 2 edges/thread, scalar weights, unroll 4 --------
// grid*256*2 == NE exactly (3125*512 = 1600000) -> no bounds checks.
__global__ __launch_bounds__(256) void edge_kernel(
    const float* __restrict__ x, float* eab,
    const int2* __restrict__ rc,
    const float* __restrict__ wt, const float* __restrict__ b2)
{
    int tA = blockIdx.x * 512 + threadIdx.x;
    int tB = tA + 256;
    int2 pA = rc[tA], pB = rc[tB];
    const float* xrA = x + (size_t)pA.x * 7;
    const float* xcA = x + (size_t)pA.y * 7;
    const float* xrB = x + (size_t)pB.x * 7;
    const float* xcB = x + (size_t)pB.y * 7;

    float A0 = xrA[0], A1 = xrA[1], A2 = xrA[2], A3 = xrA[3], A4 = xrA[4], A5 = xrA[5], A6 = xrA[6];
    float A7 = xcA[0], A8 = xcA[1], A9 = xcA[2], A10 = xcA[3], A11 = xcA[4], A12 = xcA[5], A13 = xcA[6];
    float A14 = eab[(size_t)tA * 3 + 0], A15 = eab[(size_t)tA * 3 + 1], A16 = eab[(size_t)tA * 3 + 2];
    float B0 = xrB[0], B1 = xrB[1], B2 = xrB[2], B3 = xrB[3], B4 = xrB[4], B5 = xrB[5], B6 = xrB[6];
    float B7 = xcB[0], B8 = xcB[1], B9 = xcB[2], B10 = xcB[3], B11 = xcB[4], B12 = xcB[5], B13 = xcB[6];
    float B14 = eab[(size_t)tB * 3 + 0], B15 = eab[(size_t)tB * 3 + 1], B16 = eab[(size_t)tB * 3 + 2];

    // pin gathers into VGPRs: loads cannot be sunk/rematerialized into the loop
    asm volatile("" : "+v"(A0), "+v"(A1), "+v"(A2), "+v"(A3), "+v"(A4), "+v"(A5),
                      "+v"(A6), "+v"(A7), "+v"(A8), "+v"(A9), "+v"(A10), "+v"(A11),
                      "+v"(A12), "+v"(A13), "+v"(A14), "+v"(A15), "+v"(A16));
    asm volatile("" : "+v"(B0), "+v"(B1), "+v"(B2), "+v"(B3), "+v"(B4), "+v"(B5),
                      "+v"(B6), "+v"(B7), "+v"(B8), "+v"(B9), "+v"(B10), "+v"(B11),
                      "+v"(B12), "+v"(B13), "+v"(B14), "+v"(B15), "+v"(B16));

    float aA0 = 0.f, aA1 = 0.f, aA2 = 0.f;
    float aB0 = 0.f, aB1 = 0.f, aB2 = 0.f;

    #pragma unroll 4
    for (int j = 0; j < 128; ++j) {
        const float* wr = wt + __builtin_amdgcn_readfirstlane(j * 24);
        float w[21];
        #pragma unroll
        for (int i = 0; i < 21; ++i) w[i] = wr[i];
        float hA0 = w[17], hA1 = 0.f, hB0 = w[17], hB1 = 0.f;
        hA0 += A0 * w[0];   hA1 += A1 * w[1];   hB0 += B0 * w[0];   hB1 += B1 * w[1];
        hA0 += A2 * w[2];   hA1 += A3 * w[3];   hB0 += B2 * w[2];   hB1 += B3 * w[3];
        hA0 += A4 * w[4];   hA1 += A5 * w[5];   hB0 += B4 * w[4];   hB1 += B5 * w[5];
        hA0 += A6 * w[6];   hA1 += A7 * w[7];   hB0 += B6 * w[6];   hB1 += B7 * w[7];
        hA0 += A8 * w[8];   hA1 += A9 * w[9];   hB0 += B8 * w[8];   hB1 += B9 * w[9];
        hA0 += A10 * w[10]; hA1 += A11 * w[11]; hB0 += B10 * w[10]; hB1 += B11 * w[11];
        hA0 += A12 * w[12]; hA1 += A13 * w[13]; hB0 += B12 * w[12]; hB1 += B13 * w[13];
        hA0 += A14 * w[14]; hA1 += A15 * w[15]; hB0 += B14 * w[14]; hB1 += B15 * w[15];
        hA0 += A16 * w[16];                     hB0 += B16 * w[16];
        float hA = fmaxf(hA0 + hA1, 0.f);
        float hB = fmaxf(hB0 + hB1, 0.f);
        aA0 += hA * w[18]; aB0 += hB * w[18];
        aA1 += hA * w[19]; aB1 += hB * w[19];
        aA2 += hA * w[20]; aB2 += hB * w[20];
    }

    float bb0 = b2[0], bb1 = b2[1], bb2 = b2[2];
    eab[(size_t)tA * 3 + 0] = aA0 + bb0;
    eab[(size_t)tA * 3 + 1] = aA1 + bb1;
    eab[(size_t)tA * 3 + 2] = aA2 + bb2;
    eab[(size_t)tB * 3 + 0] = aB0 + bb0;
    eab[(size_t)tB * 3 + 1] = aB1 + bb1;
    eab[(size_t)tB * 3 + 2] = aB2 + bb2;
}

// ---------------- segment reduce: 16 lanes per node ----------------
// writes nred[n][12] = [s0,s1,s2, m0,m1,m2, mean0,mean1,mean2, u0,u1, pad]
__global__ __launch_bounds__(256) void reduce_kernel(
    const float* __restrict__ eab, const unsigned* __restrict__ start,
    const float* __restrict__ u, const int* __restrict__ batch,
    float* __restrict__ nred)
{
    int gid = blockIdx.x * 256 + threadIdx.x;
    int n = gid >> 4, sub = gid & 15;
    if (n >= NN) return;
    unsigned sbeg = start[n], send = start[n + 1];

    float s0 = 0.f, s1 = 0.f, s2 = 0.f;
    float m0 = -__builtin_inff(), m1 = -__builtin_inff(), m2 = -__builtin_inff();
    for (unsigned k = sbeg + sub; k < send; k += 16) {
        float v0 = eab[(size_t)k * 3 + 0];
        float v1 = eab[(size_t)k * 3 + 1];
        float v2 = eab[(size_t)k * 3 + 2];
        s0 += v0; s1 += v1; s2 += v2;
        m0 = fmaxf(m0, v0); m1 = fmaxf(m1, v1); m2 = fmaxf(m2, v2);
    }
    #pragma unroll
    for (int msk = 1; msk < 16; msk <<= 1) {
        s0 += __shfl_xor(s0, msk, 16);
        s1 += __shfl_xor(s1, msk, 16);
        s2 += __shfl_xor(s2, msk, 16);
        m0 = fmaxf(m0, __shfl_xor(m0, msk, 16));
        m1 = fmaxf(m1, __shfl_xor(m1, msk, 16));
        m2 = fmaxf(m2, __shfl_xor(m2, msk, 16));
    }
    if (sub == 0) {
        float deg = (float)(send - sbeg);
        if (send == sbeg) { m0 = 0.f; m1 = 0.f; m2 = 0.f; }
        float inv = 1.f / fmaxf(deg, 1.f);
        int b = batch[n];
        float* o = nred + (size_t)n * 12;
        o[0] = s0; o[1] = s1; o[2] = s2;
        o[3] = m0; o[4] = m1; o[5] = m2;
        o[6] = s0 * inv; o[7] = s1 * inv; o[8] = s2 * inv;
        o[9] = u[b * 2 + 0]; o[10] = u[b * 2 + 1];
    }
}

// ---------------- node MLP: wave-per-node, weight-stationary ----------------
#define NMLP_BLOCKS 1024
#define NMLP_WAVES (NMLP_BLOCKS * 4)
__global__ __launch_bounds__(256, 4) void nodemlp_kernel(
    const float* x_in, const float* __restrict__ nred,
    const float* __restrict__ wt, const float* __restrict__ b2,
    float* x_out)
{
    int lane = threadIdx.x & 63;
    int wid = (blockIdx.x * 256 + threadIdx.x) >> 6;

    const float* ra = wt + lane * 28;
    const float* rb = wt + (lane + 64) * 28;
    float a0 = ra[0], a1 = ra[1], a2 = ra[2], a3 = ra[3], a4 = ra[4], a5 = ra[5],
          a6 = ra[6], a7 = ra[7], a8 = ra[8], a9 = ra[9], a10 = ra[10], a11 = ra[11],
          a12 = ra[12], a13 = ra[13], a14 = ra[14], a15 = ra[15], a16 = ra[16], a17 = ra[17],
          ab = ra[18], p0 = ra[19], p1 = ra[20], p2 = ra[21], p3 = ra[22], p4 = ra[23],
          p5 = ra[24], p6 = ra[25];
    float b0 = rb[0], b1 = rb[1], b2_ = rb[2], b3 = rb[3], b4 = rb[4], b5 = rb[5],
          b6 = rb[6], b7 = rb[7], b8 = rb[8], b9 = rb[9], b10 = rb[10], b11 = rb[11],
          b12 = rb[12], b13 = rb[13], b14 = rb[14], b15 = rb[15], b16 = rb[16], b17 = rb[17],
          bb = rb[18], q0 = rb[19], q1 = rb[20], q2 = rb[21], q3 = rb[22], q4 = rb[23],
          q5 = rb[24], q6 = rb[25];

    asm volatile("" : "+v"(a0), "+v"(a1), "+v"(a2), "+v"(a3), "+v"(a4), "+v"(a5),
                      "+v"(a6), "+v"(a7), "+v"(a8), "+v"(a9), "+v"(a10), "+v"(a11),
                      "+v"(a12), "+v"(a13), "+v"(a14), "+v"(a15), "+v"(a16), "+v"(a17),
                      "+v"(ab), "+v"(p0), "+v"(p1), "+v"(p2), "+v"(p3), "+v"(p4),
                      "+v"(p5), "+v"(p6));
    asm volatile("" : "+v"(b0), "+v"(b1), "+v"(b2_), "+v"(b3), "+v"(b4), "+v"(b5),
                      "+v"(b6), "+v"(b7), "+v"(b8), "+v"(b9), "+v"(b10), "+v"(b11),
                      "+v"(b12), "+v"(b13), "+v"(b14), "+v"(b15), "+v"(b16), "+v"(b17),
                      "+v"(bb), "+v"(q0), "+v"(q1), "+v"(q2), "+v"(q3), "+v"(q4),
                      "+v"(q5), "+v"(q6));

    float B0 = b2[0], B1 = b2[1], B2 = b2[2], B3 = b2[3], B4 = b2[4], B5 = b2[5], B6 = b2[6];

    const int nper = (NN + NMLP_WAVES - 1) / NMLP_WAVES;   // 25
    int n0 = wid * nper;
    int n1 = n0 + nper; if (n1 > NN) n1 = NN;

    #pragma unroll 2
    for (int n = n0; n < n1; ++n) {
        int nu = __builtin_amdgcn_readfirstlane(n);
        const float* xp = x_in + (size_t)nu * 7;
        const float* rp = nred + (size_t)nu * 12;
        float i0 = xp[0], i1 = xp[1], i2 = xp[2], i3 = xp[3], i4 = xp[4], i5 = xp[5], i6 = xp[6];
        float s0 = rp[0], s1 = rp[1], s2 = rp[2];
        float m0 = rp[3], m1 = rp[4], m2 = rp[5];
        float e0 = rp[6], e1 = rp[7], e2 = rp[8];
        float u0 = rp[9], u1 = rp[10];

        float ha = ab, hb = bb;
        ha += i0 * a0;  hb += i0 * b0;
        ha += i1 * a1;  hb += i1 * b1;
        ha += i2 * a2;  hb += i2 * b2_;
        ha += i3 * a3;  hb += i3 * b3;
        ha += i4 * a4;  hb += i4 * b4;
        ha += i5 * a5;  hb += i5 * b5;
        ha += i6 * a6;  hb += i6 * b6;
        ha += s0 * a7;  hb += s0 * b7;
        ha += s1 * a8;  hb += s1 * b8;
        ha += s2 * a9;  hb += s2 * b9;
        ha += m0 * a10; hb += m0 * b10;
        ha += m1 * a11; hb += m1 * b11;
        ha += m2 * a12; hb += m2 * b12;
        ha += e0 * a13; hb += e0 * b13;
        ha += e1 * a14; hb += e1 * b14;
        ha += e2 * a15; hb += e2 * b15;
        ha += u0 * a16; hb += u0 * b16;
        ha += u1 * a17; hb += u1 * b17;
        ha = fmaxf(ha, 0.f); hb = fmaxf(hb, 0.f);

        float c0 = ha * p0 + hb * q0;
        float c1 = ha * p1 + hb * q1;
        float c2 = ha * p2 + hb * q2;
        float c3 = ha * p3 + hb * q3;
        float c4 = ha * p4 + hb * q4;
        float c5 = ha * p5 + hb * q5;
        float c6 = ha * p6 + hb * q6;
        #pragma unroll
        for (int msk = 1; msk < 64; msk <<= 1) {
            c0 += __shfl_xor(c0, msk);
            c1 += __shfl_xor(c1, msk);
            c2 += __shfl_xor(c2, msk);
            c3 += __shfl_xor(c3, msk);
            c4 += __shfl_xor(c4, msk);
            c5 += __shfl_xor(c5, msk);
            c6 += __shfl_xor(c6, msk);
        }
        float o = c0 + B0;
        if (lane == 1) o = c1 + B1;
        if (lane == 2) o = c2 + B2;
        if (lane == 3) o = c3 + B3;
        if (lane == 4) o = c4 + B4;
        if (lane == 5) o = c5 + B5;
        if (lane == 6) o = c6 + B6;
        if (lane < 7) x_out[(size_t)nu * 7 + lane] = o;
    }
}

// ---------------- fused graph pool + output head (block per graph) ----------
__global__ __launch_bounds__(256) void pool_head_kernel(
    const float* __restrict__ x, const int* __restrict__ gstart,
    const float* __restrict__ u,
    const float* __restrict__ oW1, const float* __restrict__ ob1,
    const float* __restrict__ oW2, const float* __restrict__ ob2,
    const float* __restrict__ oW3, const float* __restrict__ ob3,
    const float* __restrict__ oW4, const float* __restrict__ ob4,
    float* __restrict__ out)
{
    int g = blockIdx.x, tid = threadIdx.x;
    int lane = tid & 63, wv = tid >> 6;
    int gs = gstart[g], ge = gstart[g + 1];

    float s0 = 0.f, s1 = 0.f, s2 = 0.f, s3 = 0.f, s4 = 0.f, s5 = 0.f, s6 = 0.f;
    float m0 = -__builtin_inff(), m1 = m0, m2 = m0, m3 = m0, m4 = m0, m5 = m0, m6 = m0;
    for (int n = gs + tid; n < ge; n += 256) {
        const float* xp = x + (size_t)n * 7;
        float v0 = xp[0], v1 = xp[1], v2 = xp[2], v3 = xp[3], v4 = xp[4], v5 = xp[5], v6 = xp[6];
        s0 += v0; s1 += v1; s2 += v2; s3 += v3; s4 += v4; s5 += v5; s6 += v6;
        m0 = fmaxf(m0, v0); m1 = fmaxf(m1, v1); m2 = fmaxf(m2, v2); m3 = fmaxf(m3, v3);
        m4 = fmaxf(m4, v4); m5 = fmaxf(m5, v5); m6 = fmaxf(m6, v6);
    }
    #pragma unroll
    for (int msk = 1; msk < 64; msk <<= 1) {
        s0 += __shfl_xor(s0, msk); s1 += __shfl_xor(s1, msk); s2 += __shfl_xor(s2, msk);
        s3 += __shfl_xor(s3, msk); s4 += __shfl_xor(s4, msk); s5 += __shfl_xor(s5, msk);
        s6 += __shfl_xor(s6, msk);
        m0 = fmaxf(m0, __shfl_xor(m0, msk)); m1 = fmaxf(m1, __shfl_xor(m1, msk));
        m2 = fmaxf(m2, __shfl_xor(m2, msk)); m3 = fmaxf(m3, __shfl_xor(m3, msk));
        m4 = fmaxf(m4, __shfl_xor(m4, msk)); m5 = fmaxf(m5, __shfl_xor(m5, msk));
        m6 = fmaxf(m6, __shfl_xor(m6, msk));
    }
    __shared__ float red[4][14];
    __shared__ float hin[23];
    __shared__ float ha[128];
    __shared__ float hbuf[128];
    if (lane == 0) {
        red[wv][0] = s0; red[wv][1] = s1; red[wv][2] = s2; red[wv][3] = s3;
        red[wv][4] = s4; red[wv][5] = s5; red[wv][6] = s6;
        red[wv][7] = m0; red[wv][8] = m1; red[wv][9] = m2; red[wv][10] = m3;
        red[wv][11] = m4; red[wv][12] = m5; red[wv][13] = m6;
    }
    __syncthreads();
    if (tid < 7) {
        float S = red[0][tid] + red[1][tid] + red[2][tid] + red[3][tid];
        float M = fmaxf(fmaxf(red[0][7 + tid], red[1][7 + tid]),
                        fmaxf(red[2][7 + tid], red[3][7 + tid]));
        float cntf = (float)(ge - gs);
        if (ge == gs) M = 0.f;
        hin[tid] = S;
        hin[7 + tid] = S / fmaxf(cntf, 1.f);
        hin[14 + tid] = M;
    }
    if (tid < 2) hin[21 + tid] = u[g * 2 + tid];
    __syncthreads();

    float h = 0.f;
    if (tid < 128) {
        h = ob1[tid];
        for (int i = 0; i < 23; ++i) h += hin[i] * oW1[i * 128 + tid];
        ha[tid] = fmaxf(h, 0.f);
    }
    __syncthreads();
    if (tid < 128) {
        h = ob2[tid];
        for (int i = 0; i < 128; ++i) h += ha[i] * oW2[i * 128 + tid];
        hbuf[tid] = fmaxf(h, 0.f);
    }
    __syncthreads();
    if (tid < 128) {
        h = ob3[tid];
        for (int i = 0; i < 128; ++i) h += hbuf[i] * oW3[i * 128 + tid];
        ha[tid] = fmaxf(h, 0.f) * oW4[tid];
    }
    __syncthreads();
    if (tid == 0) {
        float acc = ob4[0];
        for (int i = 0; i < 128; ++i) acc += ha[i];
        out[g] = acc;
    }
}

extern "C" void kernel_launch(void* const* d_in, const int* in_sizes, int n_in,
                              void* d_out, int out_size, void* d_ws, size_t ws_size,
                              hipStream_t stream) {
    const float* x         = (const float*)d_in[0];
    const float* edge_attr = (const float*)d_in[1];
    const float* u         = (const float*)d_in[2];
    const float* eW1 = (const float*)d_in[3];
    const float* eb1 = (const float*)d_in[4];
    const float* eW2 = (const float*)d_in[5];
    const float* eb2 = (const float*)d_in[6];
    const float* nW1 = (const float*)d_in[7];
    const float* nb1 = (const float*)d_in[8];
    const float* nW2 = (const float*)d_in[9];
    const float* nb2 = (const float*)d_in[10];
    const float* oW1 = (const float*)d_in[11];
    const float* ob1 = (const float*)d_in[12];
    const float* oW2 = (const float*)d_in[13];
    const float* ob2 = (const float*)d_in[14];
    const float* oW3 = (const float*)d_in[15];
    const float* ob3 = (const float*)d_in[16];
    const float* oW4 = (const float*)d_in[17];
    const float* ob4 = (const float*)d_in[18];
    const int* edge_index = (const int*)d_in[19];
    const int* batch      = (const int*)d_in[20];
    const int* row = edge_index;
    const int* col = edge_index + NE;

    // workspace layout
    float* ws        = (float*)d_ws;
    float* eab       = ws;                                  // E*3   (19.2 MB)
    float* ws_x      = eab + (size_t)NE * 3;                // N*7   (2.8 MB)
    int2*  rc        = (int2*)(ws_x + (size_t)NN * 7);      // E     (12.8 MB)
    float* nred      = (float*)(rc + (size_t)NE);           // N*12  (4.8 MB)
    unsigned* cnt    = (unsigned*)(nred + (size_t)NN * 12); // N
    unsigned* startv = cnt + NN;                            // N+1
    unsigned* cursor = startv + NN + 1;                     // N
    unsigned* bsum   = cursor + NN;                         // 512
    unsigned* boff   = bsum + 512;                          // 512
    int* gstart      = (int*)(boff + 512);                  // 257
    float* ewt       = (float*)(gstart + 260);              // 2*128*24
    float* nwt       = ewt + 2 * 128 * 24;                  // 2*128*28

    dim3 b256(256);
    dim3 ge_(NE / 256);       // 6250, exact
    dim3 ge2(NE / 512);       // 3125, exact (2 edges/thread)
    dim3 gn(NB);              // 391

    // zero cnt
    zero_kernel<<<(NN + 255) / 256, b256, 0, stream>>>((float*)cnt, NN);

    // CSR + graph-range build (no atomics for graph ranges: batch is sorted)
    count_kernel<<<ge_, b256, 0, stream>>>(col, cnt);
    gbound_kernel<<<gn, b256, 0, stream>>>(batch, gstart);
    bsum_kernel<<<gn, b256, 0, stream>>>(cnt, bsum);
    bscan_kernel<<<1, 512, 0, stream>>>(bsum, boff);
    start_kernel<<<gn, b256, 0, stream>>>(cnt, boff, startv, cursor);
    scatter_kernel<<<ge_, b256, 0, stream>>>(row, col, edge_attr, cursor, rc, eab);

    // weight prep
    {
        int t = 2 * 128 * 24 + 2 * 128 * 28;
        prep_kernel<<<(t + 255) / 256, b256, 0, stream>>>(eW1, eb1, eW2, nW1, nb1, nW2, ewt, nwt);
    }

    dim3 gr((NN * 16 + 255) / 256);   // 6250 blocks for reduce

    // ---- layer 0 ----
    edge_kernel<<<ge2, b256, 0, stream>>>(x, eab, rc, ewt, eb2);
    reduce_kernel<<<gr, b256, 0, stream>>>(eab, startv, u, batch, nred);
    nodemlp_kernel<<<NMLP_BLOCKS, b256, 0, stream>>>(x, nred, nwt, nb2, ws_x);

    // ---- layer 1 ----
    edge_kernel<<<ge2, b256, 0, stream>>>(ws_x, eab, rc, ewt + 128 * 24, eb2 + 3);
    reduce_kernel<<<gr, b256, 0, stream>>>(eab, startv, u, batch, nred);
    nodemlp_kernel<<<NMLP_BLOCKS, b256, 0, stream>>>(ws_x, nred, nwt + 128 * 28, nb2 + 7, ws_x);

    // ---- fused pool + head ----
    pool_head_kernel<<<NG, b256, 0, stream>>>(ws_x, gstart, u,
        oW1, ob1, oW2, ob2, oW3, ob3, oW4, ob4, (float*)d_out);
}